// Round 3
// baseline (292.443 us; speedup 1.0000x reference)
//
#include <hip/hip_runtime.h>

typedef __attribute__((ext_vector_type(4))) float  f32x4;
typedef __attribute__((ext_vector_type(8))) short  bf16x8;
typedef __attribute__((ext_vector_type(4))) int    i32x4;
typedef __attribute__((ext_vector_type(2))) unsigned short u16x2;
typedef __attribute__((ext_vector_type(4))) unsigned short u16x4;
typedef __attribute__((ext_vector_type(2))) unsigned int   u32x2;

#define NRES 256
#define DPAIR 128
#define NHEAD 4
#define CDIM 32
// ws layout (bytes)
#define ZN_OFF    0u            // 65536*128 bf16 = 16 MiB   (aliased as o_buf after GEMM)
#define QKG_OFF   16777216u     // 65536*384 bf16 = 48 MiB   (cols: q 0-127, k 128-255, g 256-383)
#define VT_OFF    67108864u     // [256 i][4 h][32 c][256 j] bf16 = 16 MiB
#define BIAS_OFF  83886080u     // [4][256 k][256 q] f32 = 1 MiB  (TRANSPOSED: biasT[h][k][q])
#define WCAT_OFF  84934656u     // [512][128] bf16 (q-scaled, k, v, g weights)
#define WO_OFF    85065728u     // [128][128] bf16

__device__ __forceinline__ unsigned short f2bf(float x){
  unsigned int u = __builtin_bit_cast(unsigned int, x);
  unsigned int r = (u + 0x7FFFu + ((u>>16)&1u)) >> 16;
  return (unsigned short)r;
}
__device__ __forceinline__ float bf2f(unsigned short b){
  unsigned int u = ((unsigned int)b) << 16;
  return __builtin_bit_cast(float, u);
}
__device__ __forceinline__ f32x4 fmax4(f32x4 a, f32x4 b){
  f32x4 r; r[0]=fmaxf(a[0],b[0]); r[1]=fmaxf(a[1],b[1]);
  r[2]=fmaxf(a[2],b[2]); r[3]=fmaxf(a[3],b[3]); return r;
}
// pack two f32 -> u32 of 2 bf16 (truncating) via v_perm_b32
__device__ __forceinline__ unsigned packbf2(float lo, float hi){
  return __builtin_amdgcn_perm(__builtin_bit_cast(unsigned, hi),
                               __builtin_bit_cast(unsigned, lo), 0x07060302u);
}

// ---------------- kernel 1: weight prep (fp32 -> bf16, fold q scale) ----------------
__global__ __launch_bounds__(256) void prep_kernel(
    const float* __restrict__ w_qkv, const float* __restrict__ w_g,
    const float* __restrict__ w_o,
    unsigned short* __restrict__ Wcat, unsigned short* __restrict__ Wo_bf)
{
  int idx = blockIdx.x*256 + threadIdx.x;
  if (idx < 512*128){
    int r = idx >> 7, d = idx & 127;
    float v = (r < 384) ? w_qkv[idx] : w_g[(r-384)*128 + d];
    if (r < 128) v *= 0.17677669529663689f;   // C^-0.5 folded into q rows
    Wcat[idx] = f2bf(v);
  } else if (idx < 512*128 + 128*128){
    int k = idx - 65536;
    Wo_bf[k] = f2bf(w_o[k]);
  }
}

// ---------------- kernel 2: LayerNorm (of transposed Z_raw) + pair-bias GEMV --------
// one wave per output row m = i*256+j ; Zn[m][d] = LN(Z_raw[j][i][:])[d]
// bias stored TRANSPOSED: biasT[h][k=j][q=i] so attn C-init loads are per-k-row.
__global__ __launch_bounds__(256) void ln_bias_kernel(
    const float* __restrict__ Z_raw, const float* __restrict__ ln_gamma,
    const float* __restrict__ ln_beta, const float* __restrict__ w_b,
    unsigned short* __restrict__ Zn, float* __restrict__ bias_buf)
{
  int wid = threadIdx.x >> 6, lane = threadIdx.x & 63;
  int m = blockIdx.x*4 + wid;
  int i = m >> 8, j = m & 255;
  float2 z2 = *reinterpret_cast<const float2*>(&Z_raw[((size_t)(j*256 + i))*128 + lane*2]);
  float s  = z2.x + z2.y;
  float sq = z2.x*z2.x + z2.y*z2.y;
  #pragma unroll
  for (int mk=1; mk<64; mk<<=1){ s += __shfl_xor(s, mk, 64); sq += __shfl_xor(sq, mk, 64); }
  float mu   = s * (1.0f/128.0f);
  float var  = sq*(1.0f/128.0f) - mu*mu;
  float rstd = rsqrtf(var + 1e-5f);
  float zn0 = (z2.x - mu)*rstd*ln_gamma[lane*2]   + ln_beta[lane*2];
  float zn1 = (z2.y - mu)*rstd*ln_gamma[lane*2+1] + ln_beta[lane*2+1];
  u16x2 o; o.x = f2bf(zn0); o.y = f2bf(zn1);
  *reinterpret_cast<u16x2*>(&Zn[(size_t)m*128 + lane*2]) = o;
  // pair bias: biasT[h][j][i] = Zn(i,j,:) . w_b[h,:]
  #pragma unroll
  for (int h=0; h<4; ++h){
    float d = zn0*w_b[h*128 + lane*2] + zn1*w_b[h*128 + lane*2 + 1];
    #pragma unroll
    for (int mk=1; mk<64; mk<<=1) d += __shfl_xor(d, mk, 64);
    if (lane == 0) bias_buf[((size_t)h*256 + j)*256 + i] = d;
  }
}

// ---------------- kernel 3: fused qkv+g GEMM [65536x128] x [128x512] ---------------
__global__ __launch_bounds__(256) void gemm_qkvg_kernel(
    const unsigned short* __restrict__ Zn, const unsigned short* __restrict__ Wcat,
    unsigned short* __restrict__ QKG, unsigned short* __restrict__ Vt)
{
  __shared__ __align__(16) char sA[32768];   // [128 rows][256 B] swizzled
  __shared__ __align__(16) char sB[32768];
  int rb = blockIdx.x, cb = blockIdx.y;
  int t = threadIdx.x;
  const char* gA = (const char*)Zn   + (size_t)rb*32768;
  const char* gB = (const char*)Wcat + (size_t)cb*32768;
  #pragma unroll
  for (int it=0; it<8; ++it){
    int off = it*4096 + t*16;
    int row = off >> 8;
    int swz = off ^ ((row&7)<<4);
    *reinterpret_cast<i32x4*>(sA + swz) = *reinterpret_cast<const i32x4*>(gA + off);
    *reinterpret_cast<i32x4*>(sB + swz) = *reinterpret_cast<const i32x4*>(gB + off);
  }
  __syncthreads();
  int wid = t>>6, lane = t&63;
  int wr = wid>>1, wc = wid&1;
  int lcol = lane & 15, lk16 = (lane>>4)*16;
  f32x4 acc[4][4] = {};
  #pragma unroll
  for (int ks=0; ks<4; ++ks){
    bf16x8 a[4], b[4];
    #pragma unroll
    for (int mi=0; mi<4; ++mi){
      int row = wr*64 + mi*16 + lcol;
      int off = row*256 + ks*64 + lk16;
      a[mi] = *reinterpret_cast<const bf16x8*>(sA + (off ^ ((row&7)<<4)));
    }
    #pragma unroll
    for (int ni=0; ni<4; ++ni){
      int row = wc*64 + ni*16 + lcol;
      int off = row*256 + ks*64 + lk16;
      b[ni] = *reinterpret_cast<const bf16x8*>(sB + (off ^ ((row&7)<<4)));
    }
    #pragma unroll
    for (int mi=0; mi<4; ++mi)
      #pragma unroll
      for (int ni=0; ni<4; ++ni)
        acc[mi][ni] = __builtin_amdgcn_mfma_f32_16x16x32_bf16(a[mi], b[ni], acc[mi][ni], 0,0,0);
  }
  int r0 = (lane>>4)*4;
  if (cb != 2){
    int colbase = (cb < 2 ? cb*128 : 256) + wc*64;
    #pragma unroll
    for (int mi=0; mi<4; ++mi)
      #pragma unroll
      for (int ni=0; ni<4; ++ni){
        int col  = colbase + ni*16 + lcol;
        int mrow = rb*128 + wr*64 + mi*16 + r0;
        #pragma unroll
        for (int r=0; r<4; ++r)
          QKG[(size_t)(mrow+r)*384 + col] = f2bf(acc[mi][ni][r]);
      }
  } else {
    #pragma unroll
    for (int mi=0; mi<4; ++mi)
      #pragma unroll
      for (int ni=0; ni<4; ++ni){
        int e = wc*64 + ni*16 + lcol;      // v channel: h = e>>5, c = e&31
        int h = e>>5, c = e&31;
        int mrow = rb*128 + wr*64 + mi*16 + r0;
        int i = mrow >> 8, j = mrow & 255;
        u16x4 pk;
        #pragma unroll
        for (int r=0; r<4; ++r) pk[r] = f2bf(acc[mi][ni][r]);
        *reinterpret_cast<u16x4*>(&Vt[(size_t)((i*4 + h)*32 + c)*256 + j]) = pk;
      }
  }
}

// ---------------- kernel 4: attention, one block per (i, h) ------------------------
// Swapped QK^T (S^T in regs, lane-local softmax rows), bias+mask as MFMA C-init,
// no in-loop barriers (sP wave-private), chunked sP -> 49 KiB LDS = 3 blocks/CU.
__global__ __launch_bounds__(256, 3) void attn_kernel(
    const unsigned short* __restrict__ QKG, const unsigned short* __restrict__ Vt,
    const float* __restrict__ biasT, const float* __restrict__ Z_mask,
    unsigned short* __restrict__ o_buf)
{
  __shared__ __align__(16) char sK[16384];   // [256 k-rows][64 B] swizzled
  __shared__ __align__(16) char sV[16384];   // [32 c-rows][512 B] swizzled
  __shared__ __align__(16) char sP[16384];   // per-wave 4 KiB chunk: [16 q][128 k]x2B swizzled
  __shared__ float smask[256];
  int ia = blockIdx.x >> 2, h = blockIdx.x & 3;
  int t = threadIdx.x;
  { // stage K rows (k-projection cols 128..159+h*32)
    const unsigned short* src = &QKG[(size_t)(ia*256 + t)*384 + 128 + h*32];
    #pragma unroll
    for (int c16=0; c16<4; ++c16){
      int off = t*64 + c16*16;
      *reinterpret_cast<i32x4*>(sK + (off ^ ((t&7)<<4))) =
        *reinterpret_cast<const i32x4*>(src + c16*8);
    }
  }
  { // stage V^T (contiguous 16 KiB slab)
    const char* src = (const char*)&Vt[(size_t)(ia*4 + h)*32*256];
    #pragma unroll
    for (int it=0; it<4; ++it){
      int off = (it*256 + t)*16;
      int row = off >> 9;
      *reinterpret_cast<i32x4*>(sV + (off ^ ((row&7)<<4))) =
        *reinterpret_cast<const i32x4*>(src + off);
    }
  }
  smask[t] = 1e9f * (Z_mask[(size_t)t*256 + ia] - 1.0f);
  __syncthreads();

  int wid = t>>6, lane = t&63;
  int lq = lane & 15;        // q column within 16-tile (and k-col for A-frags)
  int hi = lane >> 4;
  char* sPw = sP + wid*4096;

  // hoist Q fragments (B-operand of swapped QK^T)
  bf16x8 aq[4];
  #pragma unroll
  for (int mi=0; mi<4; ++mi){
    int q0 = wid*64 + mi*16;
    aq[mi] = *reinterpret_cast<const bf16x8*>(
        &QKG[(size_t)(ia*256 + q0 + lq)*384 + h*32 + hi*8]);
  }

  for (int mi=0; mi<4; ++mi){
    int q0 = wid*64 + mi*16;
    int q  = q0 + lq;
    f32x4 s[16];
    // C-init = biasT[h][k][q] + mask[k]
    #pragma unroll
    for (int ni=0; ni<16; ++ni){
      int k0 = ni*16 + hi*4;
      f32x4 msk = *reinterpret_cast<const f32x4*>(&smask[k0]);
      f32x4 c;
      #pragma unroll
      for (int r=0; r<4; ++r)
        c[r] = biasT[((size_t)h*256 + k0 + r)*256 + q] + msk[r];
      s[ni] = c;
    }
    // QK^T swapped: A=K-frag, B=Q-frag -> S^T tiles (row=k, col=q=lane&15)
    #pragma unroll
    for (int ni=0; ni<16; ++ni){
      int krow = ni*16 + lq;
      int off  = krow*64 + hi*16;
      bf16x8 bk = *reinterpret_cast<const bf16x8*>(sK + (off ^ ((krow&7)<<4)));
      s[ni] = __builtin_amdgcn_mfma_f32_16x16x32_bf16(bk, aq[mi], s[ni], 0,0,0);
    }
    // lane-local softmax (lane holds 64 of 256 k for its q-row; peers at ^16,^32)
    f32x4 m4 = s[0];
    #pragma unroll
    for (int ni=1; ni<16; ++ni) m4 = fmax4(m4, s[ni]);
    float mx = fmaxf(fmaxf(m4[0], m4[1]), fmaxf(m4[2], m4[3]));
    mx = fmaxf(mx, __shfl_xor(mx, 16, 64));
    mx = fmaxf(mx, __shfl_xor(mx, 32, 64));
    f32x4 sum4 = {0.f,0.f,0.f,0.f};
    #pragma unroll
    for (int ni=0; ni<16; ++ni){
      f32x4 p;
      #pragma unroll
      for (int r=0; r<4; ++r) p[r] = __expf(s[ni][r] - mx);
      s[ni] = p;
      sum4 += p;
    }
    float sum = (sum4[0]+sum4[1]) + (sum4[2]+sum4[3]);
    sum += __shfl_xor(sum, 16, 64);
    sum += __shfl_xor(sum, 32, 64);
    // redistribute 1/sum to output layout rows (q = q0 + hi*4 + r)
    float rinv[4];
    #pragma unroll
    for (int r=0; r<4; ++r)
      rinv[r] = __builtin_amdgcn_rcpf(__shfl(sum, hi*4 + r, 64));

    // pack P -> bf16 and PV, in two 128-k chunks through wave-private sP
    f32x4 oacc[2] = {};
    #pragma unroll
    for (int ch=0; ch<2; ++ch){
      #pragma unroll
      for (int nl=0; nl<8; ++nl){
        int ni = ch*8 + nl;
        u32x2 w;
        w.x = packbf2(s[ni][0], s[ni][1]);
        w.y = packbf2(s[ni][2], s[ni][3]);
        int off = lq*256 + nl*32 + hi*8;
        *reinterpret_cast<u32x2*>(sPw + (off ^ ((lq&7)<<4))) = w;
      }
      #pragma unroll
      for (int ksl=0; ksl<4; ++ksl){
        int poff = lq*256 + ksl*64 + hi*16;
        bf16x8 ap = *reinterpret_cast<const bf16x8*>(sPw + (poff ^ ((lq&7)<<4)));
        int ks = ch*4 + ksl;
        #pragma unroll
        for (int nc=0; nc<2; ++nc){
          int vrow = nc*16 + lq;
          int voff = vrow*512 + ks*64 + hi*16;
          bf16x8 bv = *reinterpret_cast<const bf16x8*>(sV + (voff ^ ((vrow&7)<<4)));
          oacc[nc] = __builtin_amdgcn_mfma_f32_16x16x32_bf16(ap, bv, oacc[nc], 0,0,0);
        }
      }
    }
    #pragma unroll
    for (int nc=0; nc<2; ++nc)
      #pragma unroll
      for (int r=0; r<4; ++r){
        int qo = q0 + hi*4 + r;
        o_buf[(size_t)(ia*256 + qo)*128 + h*32 + nc*16 + lq] = f2bf(oacc[nc][r] * rinv[r]);
      }
  }
}

// ---------------- kernel 5: gate * o @ w_o^T + out_bias + Z_raw (transposed out) ----
__global__ __launch_bounds__(256) void final_kernel(
    const unsigned short* __restrict__ QKG, const unsigned short* __restrict__ o_buf,
    const unsigned short* __restrict__ Wo_bf, const float* __restrict__ b_g,
    const float* __restrict__ out_bias, const float* __restrict__ Z_raw,
    float* __restrict__ out)
{
  __shared__ __align__(16) char sA[32768];
  __shared__ __align__(16) char sB[32768];
  int rb = blockIdx.x, t = threadIdx.x;
  #pragma unroll
  for (int it=0; it<8; ++it){
    int idx = (it*256 + t)*8;
    int row = idx >> 7, e0 = idx & 127;
    size_t m = (size_t)rb*128 + row;
    bf16x8 gv = *reinterpret_cast<const bf16x8*>(&QKG[m*384 + 256 + e0]);
    bf16x8 ov = *reinterpret_cast<const bf16x8*>(&o_buf[m*128 + e0]);
    bf16x8 av;
    #pragma unroll
    for (int jj=0; jj<8; ++jj){
      float g  = bf2f((unsigned short)gv[jj]) + b_g[e0+jj];
      float sg = 1.0f/(1.0f + __expf(-g));
      av[jj] = (short)f2bf(sg * bf2f((unsigned short)ov[jj]));
    }
    int off = idx*2;
    *reinterpret_cast<bf16x8*>(sA + (off ^ ((row&7)<<4))) = av;
    *reinterpret_cast<i32x4*>(sB + (off ^ ((row&7)<<4))) =
      *reinterpret_cast<const i32x4*>(&Wo_bf[idx]);
  }
  __syncthreads();
  int wid = t>>6, lane = t&63;
  int wr = wid>>1, wc = wid&1;
  int lcol = lane & 15, lk16 = (lane>>4)*16;
  f32x4 acc[4][4] = {};
  #pragma unroll
  for (int ks=0; ks<4; ++ks){
    bf16x8 a[4], b[4];
    #pragma unroll
    for (int mi=0; mi<4; ++mi){
      int row = wr*64 + mi*16 + lcol;
      int off = row*256 + ks*64 + lk16;
      a[mi] = *reinterpret_cast<const bf16x8*>(sA + (off ^ ((row&7)<<4)));
    }
    #pragma unroll
    for (int ni=0; ni<4; ++ni){
      int row = wc*64 + ni*16 + lcol;
      int off = row*256 + ks*64 + lk16;
      b[ni] = *reinterpret_cast<const bf16x8*>(sB + (off ^ ((row&7)<<4)));
    }
    #pragma unroll
    for (int mi=0; mi<4; ++mi)
      #pragma unroll
      for (int ni=0; ni<4; ++ni)
        acc[mi][ni] = __builtin_amdgcn_mfma_f32_16x16x32_bf16(a[mi], b[ni], acc[mi][ni], 0,0,0);
  }
  int r0 = (lane>>4)*4;
  #pragma unroll
  for (int mi=0; mi<4; ++mi)
    #pragma unroll
    for (int ni=0; ni<4; ++ni){
      int col = wc*64 + ni*16 + lcol;
      #pragma unroll
      for (int r=0; r<4; ++r){
        int mrow = rb*128 + wr*64 + mi*16 + r0 + r;
        int i = mrow >> 8, j = mrow & 255;
        size_t oidx = ((size_t)(j*256 + i))*128 + col;
        out[oidx] = acc[mi][ni][r] + out_bias[col] + Z_raw[oidx];
      }
    }
}

extern "C" void kernel_launch(void* const* d_in, const int* in_sizes, int n_in,
                              void* d_out, int out_size, void* d_ws, size_t ws_size,
                              hipStream_t stream)
{
  (void)in_sizes; (void)n_in; (void)out_size; (void)ws_size;
  const float* Z_raw    = (const float*)d_in[0];
  const float* Z_mask   = (const float*)d_in[1];
  const float* ln_gamma = (const float*)d_in[2];
  const float* ln_beta  = (const float*)d_in[3];
  const float* w_b      = (const float*)d_in[4];
  const float* w_qkv    = (const float*)d_in[5];
  const float* w_g      = (const float*)d_in[6];
  const float* b_g      = (const float*)d_in[7];
  const float* w_o      = (const float*)d_in[8];
  const float* out_bias = (const float*)d_in[9];
  float* out = (float*)d_out;

  char* ws = (char*)d_ws;
  unsigned short* Zn    = (unsigned short*)(ws + ZN_OFF);
  unsigned short* QKG   = (unsigned short*)(ws + QKG_OFF);
  unsigned short* Vt    = (unsigned short*)(ws + VT_OFF);
  float*          biasb = (float*)(ws + BIAS_OFF);
  unsigned short* Wcat  = (unsigned short*)(ws + WCAT_OFF);
  unsigned short* Wo_bf = (unsigned short*)(ws + WO_OFF);
  unsigned short* o_buf = Zn;   // alias: Zn dead after GEMM

  prep_kernel<<<dim3(320), dim3(256), 0, stream>>>(w_qkv, w_g, w_o, Wcat, Wo_bf);
  ln_bias_kernel<<<dim3(16384), dim3(256), 0, stream>>>(Z_raw, ln_gamma, ln_beta, w_b, Zn, biasb);
  gemm_qkvg_kernel<<<dim3(512, 4), dim3(256), 0, stream>>>(Zn, Wcat, QKG, Vt);
  attn_kernel<<<dim3(1024), dim3(256), 0, stream>>>(QKG, Vt, biasb, Z_mask, o_buf);
  final_kernel<<<dim3(512), dim3(256), 0, stream>>>(QKG, o_buf, Wo_bf, b_g, out_bias, Z_raw, out);
}

// Round 4
// 194.144 us; speedup vs baseline: 1.5063x; 1.5063x over previous
//
#include <hip/hip_runtime.h>

typedef __attribute__((ext_vector_type(4))) float  f32x4;
typedef __attribute__((ext_vector_type(8))) short  bf16x8;
typedef __attribute__((ext_vector_type(4))) int    i32x4;
typedef __attribute__((ext_vector_type(2))) unsigned short u16x2;
typedef __attribute__((ext_vector_type(4))) unsigned short u16x4;
typedef __attribute__((ext_vector_type(2))) unsigned int   u32x2;

#define NRES 256
#define DPAIR 128
#define NHEAD 4
#define CDIM 32
// ws layout (bytes)
#define ZN_OFF    0u            // 65536*128 bf16 = 16 MiB   (aliased as o_buf after GEMM)
#define QKG_OFF   16777216u     // 65536*384 bf16 = 48 MiB   (cols: q 0-127, k 128-255, g 256-383)
#define VT_OFF    67108864u     // [256 i][4 h][32 c][256 j] bf16 = 16 MiB
#define BIAS_OFF  83886080u     // [4][256 q][256 k] f32 = 1 MiB   (q = I-axis, k = J-axis)
#define WCAT_OFF  84934656u     // [512][128] bf16 (q-scaled, k, v, g weights)
#define WO_OFF    85065728u     // [128][128] bf16

__device__ __forceinline__ unsigned short f2bf(float x){
  unsigned int u = __builtin_bit_cast(unsigned int, x);
  unsigned int r = (u + 0x7FFFu + ((u>>16)&1u)) >> 16;
  return (unsigned short)r;
}
__device__ __forceinline__ float bf2f(unsigned short b){
  unsigned int u = ((unsigned int)b) << 16;
  return __builtin_bit_cast(float, u);
}
__device__ __forceinline__ f32x4 fmax4(f32x4 a, f32x4 b){
  f32x4 r; r[0]=fmaxf(a[0],b[0]); r[1]=fmaxf(a[1],b[1]);
  r[2]=fmaxf(a[2],b[2]); r[3]=fmaxf(a[3],b[3]); return r;
}
// pack two f32 -> u32 of 2 bf16 (truncating) via v_perm_b32
__device__ __forceinline__ unsigned packbf2(float lo, float hi){
  return __builtin_amdgcn_perm(__builtin_bit_cast(unsigned, hi),
                               __builtin_bit_cast(unsigned, lo), 0x07060302u);
}

// ---------------- kernel 1: weight prep (fp32 -> bf16, fold q scale) ----------------
__global__ __launch_bounds__(256) void prep_kernel(
    const float* __restrict__ w_qkv, const float* __restrict__ w_g,
    const float* __restrict__ w_o,
    unsigned short* __restrict__ Wcat, unsigned short* __restrict__ Wo_bf)
{
  int idx = blockIdx.x*256 + threadIdx.x;
  if (idx < 512*128){
    int r = idx >> 7, d = idx & 127;
    float v = (r < 384) ? w_qkv[idx] : w_g[(r-384)*128 + d];
    if (r < 128) v *= 0.17677669529663689f;   // C^-0.5 folded into q rows
    Wcat[idx] = f2bf(v);
  } else if (idx < 512*128 + 128*128){
    int k = idx - 65536;
    Wo_bf[k] = f2bf(w_o[k]);
  }
}

// ---------------- kernel 2: LayerNorm (of transposed Z_raw) + pair-bias GEMV --------
// one wave per output row m = i*256+j ; Zn[m][d] = LN(Z_raw[j][i][:])[d]
// bias layout [h][q=i][k=j]: attn C-init reads 4 consecutive k as one f32x4.
__global__ __launch_bounds__(256) void ln_bias_kernel(
    const float* __restrict__ Z_raw, const float* __restrict__ ln_gamma,
    const float* __restrict__ ln_beta, const float* __restrict__ w_b,
    unsigned short* __restrict__ Zn, float* __restrict__ bias_buf)
{
  int wid = threadIdx.x >> 6, lane = threadIdx.x & 63;
  int m = blockIdx.x*4 + wid;
  int i = m >> 8, j = m & 255;
  float2 z2 = *reinterpret_cast<const float2*>(&Z_raw[((size_t)(j*256 + i))*128 + lane*2]);
  float s  = z2.x + z2.y;
  float sq = z2.x*z2.x + z2.y*z2.y;
  #pragma unroll
  for (int mk=1; mk<64; mk<<=1){ s += __shfl_xor(s, mk, 64); sq += __shfl_xor(sq, mk, 64); }
  float mu   = s * (1.0f/128.0f);
  float var  = sq*(1.0f/128.0f) - mu*mu;
  float rstd = rsqrtf(var + 1e-5f);
  float zn0 = (z2.x - mu)*rstd*ln_gamma[lane*2]   + ln_beta[lane*2];
  float zn1 = (z2.y - mu)*rstd*ln_gamma[lane*2+1] + ln_beta[lane*2+1];
  u16x2 o; o.x = f2bf(zn0); o.y = f2bf(zn1);
  *reinterpret_cast<u16x2*>(&Zn[(size_t)m*128 + lane*2]) = o;
  // pair bias: bias[h][i][j] = Zn(i,j,:) . w_b[h,:]
  #pragma unroll
  for (int h=0; h<4; ++h){
    float d = zn0*w_b[h*128 + lane*2] + zn1*w_b[h*128 + lane*2 + 1];
    #pragma unroll
    for (int mk=1; mk<64; mk<<=1) d += __shfl_xor(d, mk, 64);
    if (lane == 0) bias_buf[((size_t)h*256 + i)*256 + j] = d;
  }
}

// ---------------- kernel 3: fused qkv+g GEMM [65536x128] x [128x512] ---------------
__global__ __launch_bounds__(256) void gemm_qkvg_kernel(
    const unsigned short* __restrict__ Zn, const unsigned short* __restrict__ Wcat,
    unsigned short* __restrict__ QKG, unsigned short* __restrict__ Vt)
{
  __shared__ __align__(16) char sA[32768];   // [128 rows][256 B] swizzled
  __shared__ __align__(16) char sB[32768];
  int rb = blockIdx.x, cb = blockIdx.y;
  int t = threadIdx.x;
  const char* gA = (const char*)Zn   + (size_t)rb*32768;
  const char* gB = (const char*)Wcat + (size_t)cb*32768;
  #pragma unroll
  for (int it=0; it<8; ++it){
    int off = it*4096 + t*16;
    int row = off >> 8;
    int swz = off ^ ((row&7)<<4);
    *reinterpret_cast<i32x4*>(sA + swz) = *reinterpret_cast<const i32x4*>(gA + off);
    *reinterpret_cast<i32x4*>(sB + swz) = *reinterpret_cast<const i32x4*>(gB + off);
  }
  __syncthreads();
  int wid = t>>6, lane = t&63;
  int wr = wid>>1, wc = wid&1;
  int lcol = lane & 15, lk16 = (lane>>4)*16;
  f32x4 acc[4][4] = {};
  #pragma unroll
  for (int ks=0; ks<4; ++ks){
    bf16x8 a[4], b[4];
    #pragma unroll
    for (int mi=0; mi<4; ++mi){
      int row = wr*64 + mi*16 + lcol;
      int off = row*256 + ks*64 + lk16;
      a[mi] = *reinterpret_cast<const bf16x8*>(sA + (off ^ ((row&7)<<4)));
    }
    #pragma unroll
    for (int ni=0; ni<4; ++ni){
      int row = wc*64 + ni*16 + lcol;
      int off = row*256 + ks*64 + lk16;
      b[ni] = *reinterpret_cast<const bf16x8*>(sB + (off ^ ((row&7)<<4)));
    }
    #pragma unroll
    for (int mi=0; mi<4; ++mi)
      #pragma unroll
      for (int ni=0; ni<4; ++ni)
        acc[mi][ni] = __builtin_amdgcn_mfma_f32_16x16x32_bf16(a[mi], b[ni], acc[mi][ni], 0,0,0);
  }
  int r0 = (lane>>4)*4;
  if (cb != 2){
    int colbase = (cb < 2 ? cb*128 : 256) + wc*64;
    #pragma unroll
    for (int mi=0; mi<4; ++mi)
      #pragma unroll
      for (int ni=0; ni<4; ++ni){
        int col  = colbase + ni*16 + lcol;
        int mrow = rb*128 + wr*64 + mi*16 + r0;
        #pragma unroll
        for (int r=0; r<4; ++r)
          QKG[(size_t)(mrow+r)*384 + col] = f2bf(acc[mi][ni][r]);
      }
  } else {
    #pragma unroll
    for (int mi=0; mi<4; ++mi)
      #pragma unroll
      for (int ni=0; ni<4; ++ni){
        int e = wc*64 + ni*16 + lcol;      // v channel: h = e>>5, c = e&31
        int h = e>>5, c = e&31;
        int mrow = rb*128 + wr*64 + mi*16 + r0;
        int i = mrow >> 8, j = mrow & 255;
        u16x4 pk;
        #pragma unroll
        for (int r=0; r<4; ++r) pk[r] = f2bf(acc[mi][ni][r]);
        *reinterpret_cast<u16x4*>(&Vt[(size_t)((i*4 + h)*32 + c)*256 + j]) = pk;
      }
  }
}

// ---------------- kernel 4: attention, one block per (i, h) ------------------------
// Swapped QK^T (S^T in regs, lane-local softmax rows), bias+mask as MFMA C-init
// (f32x4 loads: lane's 4 acc elems = 4 consecutive k at fixed q), no in-loop
// barriers (sP wave-private). NO launch_bounds min-occupancy arg: round-3 showed
// (256,3) forces ~84 VGPR and spills s[16] to scratch (FETCH 44->410 MB).
__global__ __launch_bounds__(256) void attn_kernel(
    const unsigned short* __restrict__ QKG, const unsigned short* __restrict__ Vt,
    const float* __restrict__ biasQ, const float* __restrict__ Z_mask,
    unsigned short* __restrict__ o_buf)
{
  __shared__ __align__(16) char sK[16384];   // [256 k-rows][64 B] swizzled
  __shared__ __align__(16) char sV[16384];   // [32 c-rows][512 B] swizzled
  __shared__ __align__(16) char sP[16384];   // per-wave 4 KiB chunk: [16 q][128 k]x2B swizzled
  __shared__ float smask[256];
  int ia = blockIdx.x >> 2, h = blockIdx.x & 3;
  int t = threadIdx.x;
  { // stage K rows (k-projection cols 128..159+h*32)
    const unsigned short* src = &QKG[(size_t)(ia*256 + t)*384 + 128 + h*32];
    #pragma unroll
    for (int c16=0; c16<4; ++c16){
      int off = t*64 + c16*16;
      *reinterpret_cast<i32x4*>(sK + (off ^ ((t&7)<<4))) =
        *reinterpret_cast<const i32x4*>(src + c16*8);
    }
  }
  { // stage V^T (contiguous 16 KiB slab)
    const char* src = (const char*)&Vt[(size_t)(ia*4 + h)*32*256];
    #pragma unroll
    for (int it=0; it<4; ++it){
      int off = (it*256 + t)*16;
      int row = off >> 9;
      *reinterpret_cast<i32x4*>(sV + (off ^ ((row&7)<<4))) =
        *reinterpret_cast<const i32x4*>(src + off);
    }
  }
  smask[t] = 1e9f * (Z_mask[(size_t)t*256 + ia] - 1.0f);
  __syncthreads();

  int wid = t>>6, lane = t&63;
  int lq = lane & 15;        // q column within 16-tile (and k-col for A-frags)
  int hi = lane >> 4;
  char* sPw = sP + wid*4096;

  // hoist Q fragments (B-operand of swapped QK^T)
  bf16x8 aq[4];
  #pragma unroll
  for (int mi=0; mi<4; ++mi){
    int q0 = wid*64 + mi*16;
    aq[mi] = *reinterpret_cast<const bf16x8*>(
        &QKG[(size_t)(ia*256 + q0 + lq)*384 + h*32 + hi*8]);
  }

  for (int mi=0; mi<4; ++mi){
    int q0 = wid*64 + mi*16;
    int q  = q0 + lq;
    const float* brow = &biasQ[((size_t)h*256 + q)*256];
    f32x4 s[16];
    // C-init = bias[h][q][k0..k0+3] + mask[k0..k0+3]   (one dwordx4 each)
    #pragma unroll
    for (int ni=0; ni<16; ++ni){
      int k0 = ni*16 + hi*4;
      f32x4 bb  = *reinterpret_cast<const f32x4*>(brow + k0);
      f32x4 msk = *reinterpret_cast<const f32x4*>(&smask[k0]);
      s[ni] = bb + msk;
    }
    // QK^T swapped: A=K-frag, B=Q-frag -> S^T tiles (row=k, col=q=lane&15)
    #pragma unroll
    for (int ni=0; ni<16; ++ni){
      int krow = ni*16 + lq;
      int off  = krow*64 + hi*16;
      bf16x8 bk = *reinterpret_cast<const bf16x8*>(sK + (off ^ ((krow&7)<<4)));
      s[ni] = __builtin_amdgcn_mfma_f32_16x16x32_bf16(bk, aq[mi], s[ni], 0,0,0);
    }
    // lane-local softmax (lane holds 64 of 256 k for its q-row; peers at ^16,^32)
    f32x4 m4 = s[0];
    #pragma unroll
    for (int ni=1; ni<16; ++ni) m4 = fmax4(m4, s[ni]);
    float mx = fmaxf(fmaxf(m4[0], m4[1]), fmaxf(m4[2], m4[3]));
    mx = fmaxf(mx, __shfl_xor(mx, 16, 64));
    mx = fmaxf(mx, __shfl_xor(mx, 32, 64));
    f32x4 sum4 = {0.f,0.f,0.f,0.f};
    #pragma unroll
    for (int ni=0; ni<16; ++ni){
      f32x4 p;
      #pragma unroll
      for (int r=0; r<4; ++r) p[r] = __expf(s[ni][r] - mx);
      s[ni] = p;
      sum4 += p;
    }
    float sum = (sum4[0]+sum4[1]) + (sum4[2]+sum4[3]);
    sum += __shfl_xor(sum, 16, 64);
    sum += __shfl_xor(sum, 32, 64);
    // redistribute 1/sum to output layout rows (q = q0 + hi*4 + r)
    float rinv[4];
    #pragma unroll
    for (int r=0; r<4; ++r)
      rinv[r] = __builtin_amdgcn_rcpf(__shfl(sum, hi*4 + r, 64));

    // pack P -> bf16 and PV, in two 128-k chunks through wave-private sP
    f32x4 oacc[2] = {};
    #pragma unroll
    for (int ch=0; ch<2; ++ch){
      #pragma unroll
      for (int nl=0; nl<8; ++nl){
        int ni = ch*8 + nl;
        u32x2 w;
        w.x = packbf2(s[ni][0], s[ni][1]);
        w.y = packbf2(s[ni][2], s[ni][3]);
        int off = lq*256 + nl*32 + hi*8;
        *reinterpret_cast<u32x2*>(sPw + (off ^ ((lq&7)<<4))) = w;
      }
      #pragma unroll
      for (int ksl=0; ksl<4; ++ksl){
        int poff = lq*256 + ksl*64 + hi*16;
        bf16x8 ap = *reinterpret_cast<const bf16x8*>(sPw + (poff ^ ((lq&7)<<4)));
        int ks = ch*4 + ksl;
        #pragma unroll
        for (int nc=0; nc<2; ++nc){
          int vrow = nc*16 + lq;
          int voff = vrow*512 + ks*64 + hi*16;
          bf16x8 bv = *reinterpret_cast<const bf16x8*>(sV + (voff ^ ((vrow&7)<<4)));
          oacc[nc] = __builtin_amdgcn_mfma_f32_16x16x32_bf16(ap, bv, oacc[nc], 0,0,0);
        }
      }
    }
    #pragma unroll
    for (int nc=0; nc<2; ++nc)
      #pragma unroll
      for (int r=0; r<4; ++r){
        int qo = q0 + hi*4 + r;
        o_buf[(size_t)(ia*256 + qo)*128 + h*32 + nc*16 + lq] = f2bf(oacc[nc][r] * rinv[r]);
      }
  }
}

// ---------------- kernel 5: gate * o @ w_o^T + out_bias + Z_raw (transposed out) ----
__global__ __launch_bounds__(256) void final_kernel(
    const unsigned short* __restrict__ QKG, const unsigned short* __restrict__ o_buf,
    const unsigned short* __restrict__ Wo_bf, const float* __restrict__ b_g,
    const float* __restrict__ out_bias, const float* __restrict__ Z_raw,
    float* __restrict__ out)
{
  __shared__ __align__(16) char sA[32768];
  __shared__ __align__(16) char sB[32768];
  int rb = blockIdx.x, t = threadIdx.x;
  #pragma unroll
  for (int it=0; it<8; ++it){
    int idx = (it*256 + t)*8;
    int row = idx >> 7, e0 = idx & 127;
    size_t m = (size_t)rb*128 + row;
    bf16x8 gv = *reinterpret_cast<const bf16x8*>(&QKG[m*384 + 256 + e0]);
    bf16x8 ov = *reinterpret_cast<const bf16x8*>(&o_buf[m*128 + e0]);
    bf16x8 av;
    #pragma unroll
    for (int jj=0; jj<8; ++jj){
      float g  = bf2f((unsigned short)gv[jj]) + b_g[e0+jj];
      float sg = 1.0f/(1.0f + __expf(-g));
      av[jj] = (short)f2bf(sg * bf2f((unsigned short)ov[jj]));
    }
    int off = idx*2;
    *reinterpret_cast<bf16x8*>(sA + (off ^ ((row&7)<<4))) = av;
    *reinterpret_cast<i32x4*>(sB + (off ^ ((row&7)<<4))) =
      *reinterpret_cast<const i32x4*>(&Wo_bf[idx]);
  }
  __syncthreads();
  int wid = t>>6, lane = t&63;
  int wr = wid>>1, wc = wid&1;
  int lcol = lane & 15, lk16 = (lane>>4)*16;
  f32x4 acc[4][4] = {};
  #pragma unroll
  for (int ks=0; ks<4; ++ks){
    bf16x8 a[4], b[4];
    #pragma unroll
    for (int mi=0; mi<4; ++mi){
      int row = wr*64 + mi*16 + lcol;
      int off = row*256 + ks*64 + lk16;
      a[mi] = *reinterpret_cast<const bf16x8*>(sA + (off ^ ((row&7)<<4)));
    }
    #pragma unroll
    for (int ni=0; ni<4; ++ni){
      int row = wc*64 + ni*16 + lcol;
      int off = row*256 + ks*64 + lk16;
      b[ni] = *reinterpret_cast<const bf16x8*>(sB + (off ^ ((row&7)<<4)));
    }
    #pragma unroll
    for (int mi=0; mi<4; ++mi)
      #pragma unroll
      for (int ni=0; ni<4; ++ni)
        acc[mi][ni] = __builtin_amdgcn_mfma_f32_16x16x32_bf16(a[mi], b[ni], acc[mi][ni], 0,0,0);
  }
  int r0 = (lane>>4)*4;
  #pragma unroll
  for (int mi=0; mi<4; ++mi)
    #pragma unroll
    for (int ni=0; ni<4; ++ni){
      int col = wc*64 + ni*16 + lcol;
      #pragma unroll
      for (int r=0; r<4; ++r){
        int mrow = rb*128 + wr*64 + mi*16 + r0 + r;
        int i = mrow >> 8, j = mrow & 255;
        size_t oidx = ((size_t)(j*256 + i))*128 + col;
        out[oidx] = acc[mi][ni][r] + out_bias[col] + Z_raw[oidx];
      }
    }
}

extern "C" void kernel_launch(void* const* d_in, const int* in_sizes, int n_in,
                              void* d_out, int out_size, void* d_ws, size_t ws_size,
                              hipStream_t stream)
{
  (void)in_sizes; (void)n_in; (void)out_size; (void)ws_size;
  const float* Z_raw    = (const float*)d_in[0];
  const float* Z_mask   = (const float*)d_in[1];
  const float* ln_gamma = (const float*)d_in[2];
  const float* ln_beta  = (const float*)d_in[3];
  const float* w_b      = (const float*)d_in[4];
  const float* w_qkv    = (const float*)d_in[5];
  const float* w_g      = (const float*)d_in[6];
  const float* b_g      = (const float*)d_in[7];
  const float* w_o      = (const float*)d_in[8];
  const float* out_bias = (const float*)d_in[9];
  float* out = (float*)d_out;

  char* ws = (char*)d_ws;
  unsigned short* Zn    = (unsigned short*)(ws + ZN_OFF);
  unsigned short* QKG   = (unsigned short*)(ws + QKG_OFF);
  unsigned short* Vt    = (unsigned short*)(ws + VT_OFF);
  float*          biasb = (float*)(ws + BIAS_OFF);
  unsigned short* Wcat  = (unsigned short*)(ws + WCAT_OFF);
  unsigned short* Wo_bf = (unsigned short*)(ws + WO_OFF);
  unsigned short* o_buf = Zn;   // alias: Zn dead after GEMM

  prep_kernel<<<dim3(320), dim3(256), 0, stream>>>(w_qkv, w_g, w_o, Wcat, Wo_bf);
  ln_bias_kernel<<<dim3(16384), dim3(256), 0, stream>>>(Z_raw, ln_gamma, ln_beta, w_b, Zn, biasb);
  gemm_qkvg_kernel<<<dim3(512, 4), dim3(256), 0, stream>>>(Zn, Wcat, QKG, Vt);
  attn_kernel<<<dim3(1024), dim3(256), 0, stream>>>(QKG, Vt, biasb, Z_mask, o_buf);
  final_kernel<<<dim3(512), dim3(256), 0, stream>>>(QKG, o_buf, Wo_bf, b_g, out_bias, Z_raw, out);
}

// Round 6
// 146.814 us; speedup vs baseline: 1.9919x; 1.3224x over previous
//
#include <hip/hip_runtime.h>

typedef __attribute__((ext_vector_type(4))) float  f32x4;
typedef __attribute__((ext_vector_type(8))) short  bf16x8;
typedef __attribute__((ext_vector_type(4))) int    i32x4;
typedef __attribute__((ext_vector_type(2))) unsigned short u16x2;
typedef __attribute__((ext_vector_type(4))) unsigned short u16x4;
typedef __attribute__((ext_vector_type(2))) unsigned int   u32x2;

// ws layout (bytes)
#define ZN_OFF    0u            // 65536*128 bf16 = 16 MiB (aliased as o_buf after GEMM)
#define QSEP_OFF  16777216u     // [256 i][4 h][256 j][32 c] bf16 = 16 MiB (q, scale folded)
#define KSEP_OFF  33554432u     // [256 i][4 h][256 j][32 c] bf16 = 16 MiB
#define GBUF_OFF  50331648u     // [65536][128] bf16 = 16 MiB (gate)
#define VT_OFF    67108864u     // [256 i][4 h][32 c][256 j] bf16 = 16 MiB
#define BIAS_OFF  83886080u     // [4 h][64 k4][256 q][4] f32 = 1 MiB (gathered-transpose)
#define WCAT_OFF  84934656u     // [512][128] bf16
#define WO_OFF    85065728u     // [128][128] bf16

__device__ __forceinline__ unsigned short f2bf(float x){
  unsigned int u = __builtin_bit_cast(unsigned int, x);
  unsigned int r = (u + 0x7FFFu + ((u>>16)&1u)) >> 16;
  return (unsigned short)r;
}
__device__ __forceinline__ float bf2f(unsigned short b){
  unsigned int u = ((unsigned int)b) << 16;
  return __builtin_bit_cast(float, u);
}
__device__ __forceinline__ f32x4 fmax4(f32x4 a, f32x4 b){
  f32x4 r; r[0]=fmaxf(a[0],b[0]); r[1]=fmaxf(a[1],b[1]);
  r[2]=fmaxf(a[2],b[2]); r[3]=fmaxf(a[3],b[3]); return r;
}
__device__ __forceinline__ unsigned packbf2(float lo, float hi){
  return __builtin_amdgcn_perm(__builtin_bit_cast(unsigned, hi),
                               __builtin_bit_cast(unsigned, lo), 0x07060302u);
}

// ---------------- kernel 1: weight prep (fp32 -> bf16, fold q scale) ----------------
__global__ __launch_bounds__(256) void prep_kernel(
    const float* __restrict__ w_qkv, const float* __restrict__ w_g,
    const float* __restrict__ w_o,
    unsigned short* __restrict__ Wcat, unsigned short* __restrict__ Wo_bf)
{
  int idx = blockIdx.x*256 + threadIdx.x;
  if (idx < 512*128){
    int r = idx >> 7, d = idx & 127;
    float v = (r < 384) ? w_qkv[idx] : w_g[(r-384)*128 + d];
    if (r < 128) v *= 0.17677669529663689f;   // C^-0.5 folded into q rows
    Wcat[idx] = f2bf(v);
  } else if (idx < 512*128 + 128*128){
    int k = idx - 65536;
    Wo_bf[k] = f2bf(w_o[k]);
  }
}

// ---------------- kernel 2: LayerNorm (of transposed Z_raw) + pair-bias GEMV --------
// bias stored gathered-transposed: bias4[h][k>>2][q][k&3] so a lane's 4 acc
// elements (4 consecutive k at fixed q) are one f32x4, 256B-contiguous per
// 16-lane group in attn.
__global__ __launch_bounds__(256) void ln_bias_kernel(
    const float* __restrict__ Z_raw, const float* __restrict__ ln_gamma,
    const float* __restrict__ ln_beta, const float* __restrict__ w_b,
    unsigned short* __restrict__ Zn, float* __restrict__ bias_buf)
{
  int wid = threadIdx.x >> 6, lane = threadIdx.x & 63;
  int m = blockIdx.x*4 + wid;
  int i = m >> 8, j = m & 255;
  float2 z2 = *reinterpret_cast<const float2*>(&Z_raw[((size_t)(j*256 + i))*128 + lane*2]);
  float s  = z2.x + z2.y;
  float sq = z2.x*z2.x + z2.y*z2.y;
  #pragma unroll
  for (int mk=1; mk<64; mk<<=1){ s += __shfl_xor(s, mk, 64); sq += __shfl_xor(sq, mk, 64); }
  float mu   = s * (1.0f/128.0f);
  float var  = sq*(1.0f/128.0f) - mu*mu;
  float rstd = rsqrtf(var + 1e-5f);
  float zn0 = (z2.x - mu)*rstd*ln_gamma[lane*2]   + ln_beta[lane*2];
  float zn1 = (z2.y - mu)*rstd*ln_gamma[lane*2+1] + ln_beta[lane*2+1];
  u16x2 o; o.x = f2bf(zn0); o.y = f2bf(zn1);
  *reinterpret_cast<u16x2*>(&Zn[(size_t)m*128 + lane*2]) = o;
  // pair bias value for (q=i, k=j), head h
  #pragma unroll
  for (int h=0; h<4; ++h){
    float d = zn0*w_b[h*128 + lane*2] + zn1*w_b[h*128 + lane*2 + 1];
    #pragma unroll
    for (int mk=1; mk<64; mk<<=1) d += __shfl_xor(d, mk, 64);
    if (lane == 0)
      bias_buf[(((size_t)h*64 + (j>>2))*256 + i)*4 + (j&3)] = d;
  }
}

// ---------------- kernel 3: fused qkv+g GEMM [65536x128] x [128x512] ---------------
// cb 0: q -> Qsep[i][h][j][c] ; cb 1: k -> Ksep ; cb 2: v -> Vt ; cb 3: g -> Gbuf
__global__ __launch_bounds__(256) void gemm_qkvg_kernel(
    const unsigned short* __restrict__ Zn, const unsigned short* __restrict__ Wcat,
    unsigned short* __restrict__ Qsep, unsigned short* __restrict__ Ksep,
    unsigned short* __restrict__ Gbuf, unsigned short* __restrict__ Vt)
{
  __shared__ __align__(16) char sA[32768];   // [128 rows][256 B] swizzled
  __shared__ __align__(16) char sB[32768];
  int rb = blockIdx.x, cb = blockIdx.y;
  int t = threadIdx.x;
  const char* gA = (const char*)Zn   + (size_t)rb*32768;
  const char* gB = (const char*)Wcat + (size_t)cb*32768;
  #pragma unroll
  for (int it=0; it<8; ++it){
    int off = it*4096 + t*16;
    int row = off >> 8;
    int swz = off ^ ((row&7)<<4);
    *reinterpret_cast<i32x4*>(sA + swz) = *reinterpret_cast<const i32x4*>(gA + off);
    *reinterpret_cast<i32x4*>(sB + swz) = *reinterpret_cast<const i32x4*>(gB + off);
  }
  __syncthreads();
  int wid = t>>6, lane = t&63;
  int wr = wid>>1, wc = wid&1;
  int lcol = lane & 15, lk16 = (lane>>4)*16;
  f32x4 acc[4][4] = {};
  #pragma unroll
  for (int ks=0; ks<4; ++ks){
    bf16x8 a[4], b[4];
    #pragma unroll
    for (int mi=0; mi<4; ++mi){
      int row = wr*64 + mi*16 + lcol;
      int off = row*256 + ks*64 + lk16;
      a[mi] = *reinterpret_cast<const bf16x8*>(sA + (off ^ ((row&7)<<4)));
    }
    #pragma unroll
    for (int ni=0; ni<4; ++ni){
      int row = wc*64 + ni*16 + lcol;
      int off = row*256 + ks*64 + lk16;
      b[ni] = *reinterpret_cast<const bf16x8*>(sB + (off ^ ((row&7)<<4)));
    }
    #pragma unroll
    for (int mi=0; mi<4; ++mi)
      #pragma unroll
      for (int ni=0; ni<4; ++ni)
        acc[mi][ni] = __builtin_amdgcn_mfma_f32_16x16x32_bf16(a[mi], b[ni], acc[mi][ni], 0,0,0);
  }
  int r0 = (lane>>4)*4;
  if (cb <= 1){
    unsigned short* __restrict__ dst = cb ? Ksep : Qsep;
    #pragma unroll
    for (int mi=0; mi<4; ++mi)
      #pragma unroll
      for (int ni=0; ni<4; ++ni){
        int e = wc*64 + ni*16 + lcol;      // h = e>>5, c = e&31
        int hh = e>>5, c = e&31;
        int mrow = rb*128 + wr*64 + mi*16 + r0;
        #pragma unroll
        for (int r=0; r<4; ++r){
          int m = mrow + r;
          int i2 = m >> 8, j2 = m & 255;
          dst[(size_t)((i2*4 + hh)*256 + j2)*32 + c] = f2bf(acc[mi][ni][r]);
        }
      }
  } else if (cb == 3){
    #pragma unroll
    for (int mi=0; mi<4; ++mi)
      #pragma unroll
      for (int ni=0; ni<4; ++ni){
        int col = wc*64 + ni*16 + lcol;
        int mrow = rb*128 + wr*64 + mi*16 + r0;
        #pragma unroll
        for (int r=0; r<4; ++r)
          Gbuf[(size_t)(mrow+r)*128 + col] = f2bf(acc[mi][ni][r]);
      }
  } else { // cb == 2: v, transposed per (i,h)
    #pragma unroll
    for (int mi=0; mi<4; ++mi)
      #pragma unroll
      for (int ni=0; ni<4; ++ni){
        int e = wc*64 + ni*16 + lcol;
        int hh = e>>5, c = e&31;
        int mrow = rb*128 + wr*64 + mi*16 + r0;
        int i2 = mrow >> 8, j2 = mrow & 255;
        u16x4 pk;
        #pragma unroll
        for (int r=0; r<4; ++r) pk[r] = f2bf(acc[mi][ni][r]);
        *reinterpret_cast<u16x4*>(&Vt[(size_t)((i2*4 + hh)*32 + c)*256 + j2]) = pk;
      }
  }
}

// ---------------- kernel 4: attention, one block per (i, h) ------------------------
// Swapped QK^T (S^T lane-local softmax), online softmax over two 128-k halves.
// FIX (round 5 bug): the online rescale factor sc belongs to q-row (lane&15),
// but oacc rows are q = hi*4+r -> redistribute sc via __shfl(sc, hi*4+r) exactly
// like rinv. Round-5 applied the lane's own sc to all oacc rows -> absmax 1.86.
__global__ __launch_bounds__(256) void attn_kernel(
    const unsigned short* __restrict__ Qsep, const unsigned short* __restrict__ Ksep,
    const unsigned short* __restrict__ Vt, const float* __restrict__ bias4,
    const float* __restrict__ Z_mask, unsigned short* __restrict__ o_buf)
{
  __shared__ __align__(16) char sK[16384];   // [256 k-rows][64 B] swizzled
  __shared__ __align__(16) char sV[16384];   // [32 c-rows][512 B] swizzled
  __shared__ __align__(16) char sP[4096];    // per-wave 1 KiB: [16 q][64 B] natural
  __shared__ float smask[256];
  int ia = blockIdx.x >> 2, h = blockIdx.x & 3;
  int t = threadIdx.x;
  {
    const char* srcK = (const char*)&Ksep[(size_t)((ia*4 + h)*256)*32];
    const char* srcV = (const char*)&Vt[(size_t)((ia*4 + h)*32)*256];
    #pragma unroll
    for (int it=0; it<4; ++it){
      int off = (it*256 + t)*16;
      int rowK = off >> 6;
      *reinterpret_cast<i32x4*>(sK + (off ^ ((rowK&7)<<4))) =
        *reinterpret_cast<const i32x4*>(srcK + off);
      int rowV = off >> 9;
      *reinterpret_cast<i32x4*>(sV + (off ^ ((rowV&7)<<4))) =
        *reinterpret_cast<const i32x4*>(srcV + off);
    }
  }
  smask[t] = 1e9f * (Z_mask[(size_t)t*256 + ia] - 1.0f);
  __syncthreads();

  int wid = t>>6, lane = t&63;
  int lq = lane & 15;
  int hi = lane >> 4;
  char* sPw = sP + wid*1024;
  const f32x4* b4 = reinterpret_cast<const f32x4*>(bias4);

  #pragma unroll 1
  for (int mi=0; mi<4; ++mi){
    int q0 = wid*64 + mi*16;
    int q  = q0 + lq;
    bf16x8 aq = *reinterpret_cast<const bf16x8*>(
        &Qsep[(size_t)((ia*4 + h)*256 + q)*32 + hi*8]);
    f32x4 oacc[2] = {};
    float mrun = 0.f, lsum = 0.f;
    #pragma unroll
    for (int half=0; half<2; ++half){
      f32x4 s[8];
      // C-init = bias4[h][g][q] + mask[k0..k0+3]
      #pragma unroll
      for (int ni=0; ni<8; ++ni){
        int g  = half*32 + ni*4 + hi;
        int k0 = half*128 + ni*16 + hi*4;
        f32x4 bb  = b4[(size_t)(h*64 + g)*256 + q];
        f32x4 msk = *reinterpret_cast<const f32x4*>(&smask[k0]);
        s[ni] = bb + msk;
      }
      // swapped QK^T: A=K-frag, B=Q-frag -> S^T (row=k, col=q)
      #pragma unroll
      for (int ni=0; ni<8; ++ni){
        int krow = half*128 + ni*16 + lq;
        int off  = krow*64 + hi*16;
        bf16x8 bk = *reinterpret_cast<const bf16x8*>(sK + (off ^ ((krow&7)<<4)));
        s[ni] = __builtin_amdgcn_mfma_f32_16x16x32_bf16(bk, aq, s[ni], 0,0,0);
      }
      // row max for q-row (q0+lq): lane-local + peers at ^16, ^32
      f32x4 m4 = fmax4(s[0], s[1]);
      m4 = fmax4(m4, fmax4(s[2], s[3]));
      m4 = fmax4(m4, fmax4(s[4], s[5]));
      m4 = fmax4(m4, fmax4(s[6], s[7]));
      float mx = fmaxf(fmaxf(m4[0], m4[1]), fmaxf(m4[2], m4[3]));
      mx = fmaxf(mx, __shfl_xor(mx, 16, 64));
      mx = fmaxf(mx, __shfl_xor(mx, 32, 64));
      if (half == 0){
        mrun = mx;
      } else {
        float mnew = fmaxf(mrun, mx);
        float sc = __expf(mrun - mnew);   // scale for q-row (q0+lq)
        lsum *= sc;
        mrun = mnew;
        // oacc rows are q = q0 + hi*4 + r -> fetch those rows' scales
        #pragma unroll
        for (int r=0; r<4; ++r){
          float scr = __shfl(sc, hi*4 + r, 64);
          oacc[0][r] *= scr;
          oacc[1][r] *= scr;
        }
      }
      // exp + partial sum
      f32x4 sum4 = {0.f,0.f,0.f,0.f};
      #pragma unroll
      for (int ni=0; ni<8; ++ni){
        f32x4 p;
        #pragma unroll
        for (int r=0; r<4; ++r) p[r] = __expf(s[ni][r] - mrun);
        s[ni] = p;
        sum4 += p;
      }
      lsum += (sum4[0]+sum4[1]) + (sum4[2]+sum4[3]);
      // pack P -> bf16 through wave-private sP, PV in 32-k chunks
      #pragma unroll
      for (int ck=0; ck<4; ++ck){
        #pragma unroll
        for (int nl=0; nl<2; ++nl){
          int ni = ck*2 + nl;
          u32x2 w;
          w.x = packbf2(s[ni][0], s[ni][1]);
          w.y = packbf2(s[ni][2], s[ni][3]);
          *reinterpret_cast<u32x2*>(sPw + lq*64 + nl*32 + hi*8) = w;
        }
        bf16x8 ap = *reinterpret_cast<const bf16x8*>(sPw + lq*64 + hi*16);
        int ks = half*4 + ck;
        #pragma unroll
        for (int nc=0; nc<2; ++nc){
          int vrow = nc*16 + lq;
          int voff = vrow*512 + ks*64 + hi*16;
          bf16x8 bv = *reinterpret_cast<const bf16x8*>(sV + (voff ^ ((vrow&7)<<4)));
          oacc[nc] = __builtin_amdgcn_mfma_f32_16x16x32_bf16(ap, bv, oacc[nc], 0,0,0);
        }
      }
    }
    float sum = lsum;
    sum += __shfl_xor(sum, 16, 64);
    sum += __shfl_xor(sum, 32, 64);
    float rinv[4];
    #pragma unroll
    for (int r=0; r<4; ++r)
      rinv[r] = __builtin_amdgcn_rcpf(__shfl(sum, hi*4 + r, 64));
    #pragma unroll
    for (int nc=0; nc<2; ++nc)
      #pragma unroll
      for (int r=0; r<4; ++r){
        int qo = q0 + hi*4 + r;
        o_buf[(size_t)(ia*256 + qo)*128 + h*32 + nc*16 + lq] = f2bf(oacc[nc][r] * rinv[r]);
      }
  }
}

// ---------------- kernel 5: gate * o @ w_o^T + out_bias + Z_raw (transposed out) ----
__global__ __launch_bounds__(256) void final_kernel(
    const unsigned short* __restrict__ Gbuf, const unsigned short* __restrict__ o_buf,
    const unsigned short* __restrict__ Wo_bf, const float* __restrict__ b_g,
    const float* __restrict__ out_bias, const float* __restrict__ Z_raw,
    float* __restrict__ out)
{
  __shared__ __align__(16) char sA[32768];
  __shared__ __align__(16) char sB[32768];
  int rb = blockIdx.x, t = threadIdx.x;
  #pragma unroll
  for (int it=0; it<8; ++it){
    int idx = (it*256 + t)*8;
    int row = idx >> 7, e0 = idx & 127;
    size_t m = (size_t)rb*128 + row;
    bf16x8 gv = *reinterpret_cast<const bf16x8*>(&Gbuf[m*128 + e0]);
    bf16x8 ov = *reinterpret_cast<const bf16x8*>(&o_buf[m*128 + e0]);
    bf16x8 av;
    #pragma unroll
    for (int jj=0; jj<8; ++jj){
      float g  = bf2f((unsigned short)gv[jj]) + b_g[e0+jj];
      float sg = 1.0f/(1.0f + __expf(-g));
      av[jj] = (short)f2bf(sg * bf2f((unsigned short)ov[jj]));
    }
    int off = idx*2;
    *reinterpret_cast<bf16x8*>(sA + (off ^ ((row&7)<<4))) = av;
    *reinterpret_cast<i32x4*>(sB + (off ^ ((row&7)<<4))) =
      *reinterpret_cast<const i32x4*>(&Wo_bf[idx]);
  }
  __syncthreads();
  int wid = t>>6, lane = t&63;
  int wr = wid>>1, wc = wid&1;
  int lcol = lane & 15, lk16 = (lane>>4)*16;
  f32x4 acc[4][4] = {};
  #pragma unroll
  for (int ks=0; ks<4; ++ks){
    bf16x8 a[4], b[4];
    #pragma unroll
    for (int mi=0; mi<4; ++mi){
      int row = wr*64 + mi*16 + lcol;
      int off = row*256 + ks*64 + lk16;
      a[mi] = *reinterpret_cast<const bf16x8*>(sA + (off ^ ((row&7)<<4)));
    }
    #pragma unroll
    for (int ni=0; ni<4; ++ni){
      int row = wc*64 + ni*16 + lcol;
      int off = row*256 + ks*64 + lk16;
      b[ni] = *reinterpret_cast<const bf16x8*>(sB + (off ^ ((row&7)<<4)));
    }
    #pragma unroll
    for (int mi=0; mi<4; ++mi)
      #pragma unroll
      for (int ni=0; ni<4; ++ni)
        acc[mi][ni] = __builtin_amdgcn_mfma_f32_16x16x32_bf16(a[mi], b[ni], acc[mi][ni], 0,0,0);
  }
  int r0 = (lane>>4)*4;
  #pragma unroll
  for (int mi=0; mi<4; ++mi)
    #pragma unroll
    for (int ni=0; ni<4; ++ni){
      int col = wc*64 + ni*16 + lcol;
      #pragma unroll
      for (int r=0; r<4; ++r){
        int mrow = rb*128 + wr*64 + mi*16 + r0 + r;
        int i = mrow >> 8, j = mrow & 255;
        size_t oidx = ((size_t)(j*256 + i))*128 + col;
        out[oidx] = acc[mi][ni][r] + out_bias[col] + Z_raw[oidx];
      }
    }
}

extern "C" void kernel_launch(void* const* d_in, const int* in_sizes, int n_in,
                              void* d_out, int out_size, void* d_ws, size_t ws_size,
                              hipStream_t stream)
{
  (void)in_sizes; (void)n_in; (void)out_size; (void)ws_size;
  const float* Z_raw    = (const float*)d_in[0];
  const float* Z_mask   = (const float*)d_in[1];
  const float* ln_gamma = (const float*)d_in[2];
  const float* ln_beta  = (const float*)d_in[3];
  const float* w_b      = (const float*)d_in[4];
  const float* w_qkv    = (const float*)d_in[5];
  const float* w_g      = (const float*)d_in[6];
  const float* b_g      = (const float*)d_in[7];
  const float* w_o      = (const float*)d_in[8];
  const float* out_bias = (const float*)d_in[9];
  float* out = (float*)d_out;

  char* ws = (char*)d_ws;
  unsigned short* Zn    = (unsigned short*)(ws + ZN_OFF);
  unsigned short* Qsep  = (unsigned short*)(ws + QSEP_OFF);
  unsigned short* Ksep  = (unsigned short*)(ws + KSEP_OFF);
  unsigned short* Gbuf  = (unsigned short*)(ws + GBUF_OFF);
  unsigned short* Vt    = (unsigned short*)(ws + VT_OFF);
  float*          biasb = (float*)(ws + BIAS_OFF);
  unsigned short* Wcat  = (unsigned short*)(ws + WCAT_OFF);
  unsigned short* Wo_bf = (unsigned short*)(ws + WO_OFF);
  unsigned short* o_buf = Zn;   // alias: Zn dead after GEMM

  prep_kernel<<<dim3(320), dim3(256), 0, stream>>>(w_qkv, w_g, w_o, Wcat, Wo_bf);
  ln_bias_kernel<<<dim3(16384), dim3(256), 0, stream>>>(Z_raw, ln_gamma, ln_beta, w_b, Zn, biasb);
  gemm_qkvg_kernel<<<dim3(512, 4), dim3(256), 0, stream>>>(Zn, Wcat, Qsep, Ksep, Gbuf, Vt);
  attn_kernel<<<dim3(1024), dim3(256), 0, stream>>>(Qsep, Ksep, Vt, biasb, Z_mask, o_buf);
  final_kernel<<<dim3(512), dim3(256), 0, stream>>>(Gbuf, o_buf, Wo_bf, b_g, out_bias, Z_raw, out);
}

// Round 7
// 113.810 us; speedup vs baseline: 2.5696x; 1.2900x over previous
//
#include <hip/hip_runtime.h>

typedef __attribute__((ext_vector_type(4))) float  f32x4;
typedef __attribute__((ext_vector_type(8))) short  bf16x8;
typedef __attribute__((ext_vector_type(4))) int    i32x4;
typedef __attribute__((ext_vector_type(2))) unsigned short u16x2;
typedef __attribute__((ext_vector_type(4))) unsigned short u16x4;
typedef __attribute__((ext_vector_type(2))) unsigned int   u32x2;

// ws layout (bytes)
#define ZN_OFF    0u            // 65536*128 bf16 = 16 MiB (aliased as o_buf after GEMM)
#define QSEP_OFF  16777216u     // [256 i][4 h][256 j][32 c] bf16 = 16 MiB (q, scale folded)
#define KSEP_OFF  33554432u     // [256 i][4 h][256 j][32 c] bf16 = 16 MiB
#define GBUF_OFF  50331648u     // [65536][128] bf16 = 16 MiB (gate)
#define VT_OFF    67108864u     // [256 i][4 h][32 c][256 j] bf16 = 16 MiB
#define BIAS_OFF  83886080u     // [4 h][64 k4][256 q][4] f32 = 1 MiB (gathered-transpose)
#define WCAT_OFF  84934656u     // [512][128] bf16
#define WO_OFF    85065728u     // [128][128] bf16

__device__ __forceinline__ unsigned short f2bf(float x){
  unsigned int u = __builtin_bit_cast(unsigned int, x);
  unsigned int r = (u + 0x7FFFu + ((u>>16)&1u)) >> 16;
  return (unsigned short)r;
}
__device__ __forceinline__ float bf2f(unsigned short b){
  unsigned int u = ((unsigned int)b) << 16;
  return __builtin_bit_cast(float, u);
}
__device__ __forceinline__ f32x4 fmax4(f32x4 a, f32x4 b){
  f32x4 r; r[0]=fmaxf(a[0],b[0]); r[1]=fmaxf(a[1],b[1]);
  r[2]=fmaxf(a[2],b[2]); r[3]=fmaxf(a[3],b[3]); return r;
}
__device__ __forceinline__ unsigned packbf2(float lo, float hi){
  return __builtin_amdgcn_perm(__builtin_bit_cast(unsigned, hi),
                               __builtin_bit_cast(unsigned, lo), 0x07060302u);
}

// ---------------- kernel 1: weight prep (fp32 -> bf16, fold q scale) ----------------
__global__ __launch_bounds__(256) void prep_kernel(
    const float* __restrict__ w_qkv, const float* __restrict__ w_g,
    const float* __restrict__ w_o,
    unsigned short* __restrict__ Wcat, unsigned short* __restrict__ Wo_bf)
{
  int idx = blockIdx.x*256 + threadIdx.x;
  if (idx < 512*128){
    int r = idx >> 7, d = idx & 127;
    float v = (r < 384) ? w_qkv[idx] : w_g[(r-384)*128 + d];
    if (r < 128) v *= 0.17677669529663689f;   // C^-0.5 folded into q rows
    Wcat[idx] = f2bf(v);
  } else if (idx < 512*128 + 128*128){
    int k = idx - 65536;
    Wo_bf[k] = f2bf(w_o[k]);
  }
}

// ---------------- kernel 2: LayerNorm (of transposed Z_raw) + pair-bias GEMV --------
// bias stored gathered-transposed: bias4[h][k>>2][q][k&3] so a lane's 4 acc
// elements (4 consecutive k at fixed q) are one f32x4, 256B-contiguous per
// 16-lane group in attn.
__global__ __launch_bounds__(256) void ln_bias_kernel(
    const float* __restrict__ Z_raw, const float* __restrict__ ln_gamma,
    const float* __restrict__ ln_beta, const float* __restrict__ w_b,
    unsigned short* __restrict__ Zn, float* __restrict__ bias_buf)
{
  int wid = threadIdx.x >> 6, lane = threadIdx.x & 63;
  int m = blockIdx.x*4 + wid;
  int i = m >> 8, j = m & 255;
  float2 z2 = *reinterpret_cast<const float2*>(&Z_raw[((size_t)(j*256 + i))*128 + lane*2]);
  float s  = z2.x + z2.y;
  float sq = z2.x*z2.x + z2.y*z2.y;
  #pragma unroll
  for (int mk=1; mk<64; mk<<=1){ s += __shfl_xor(s, mk, 64); sq += __shfl_xor(sq, mk, 64); }
  float mu   = s * (1.0f/128.0f);
  float var  = sq*(1.0f/128.0f) - mu*mu;
  float rstd = rsqrtf(var + 1e-5f);
  float zn0 = (z2.x - mu)*rstd*ln_gamma[lane*2]   + ln_beta[lane*2];
  float zn1 = (z2.y - mu)*rstd*ln_gamma[lane*2+1] + ln_beta[lane*2+1];
  u16x2 o; o.x = f2bf(zn0); o.y = f2bf(zn1);
  *reinterpret_cast<u16x2*>(&Zn[(size_t)m*128 + lane*2]) = o;
  // pair bias value for (q=i, k=j), head h
  #pragma unroll
  for (int h=0; h<4; ++h){
    float d = zn0*w_b[h*128 + lane*2] + zn1*w_b[h*128 + lane*2 + 1];
    #pragma unroll
    for (int mk=1; mk<64; mk<<=1) d += __shfl_xor(d, mk, 64);
    if (lane == 0)
      bias_buf[(((size_t)h*64 + (j>>2))*256 + i)*4 + (j&3)] = d;
  }
}

// ---------------- kernel 3: fused qkv+g GEMM [65536x128] x [128x512] ---------------
// cb 0: q -> Qsep[i][h][j][c] ; cb 1: k -> Ksep ; cb 2: v -> Vt ; cb 3: g -> Gbuf
__global__ __launch_bounds__(256) void gemm_qkvg_kernel(
    const unsigned short* __restrict__ Zn, const unsigned short* __restrict__ Wcat,
    unsigned short* __restrict__ Qsep, unsigned short* __restrict__ Ksep,
    unsigned short* __restrict__ Gbuf, unsigned short* __restrict__ Vt)
{
  __shared__ __align__(16) char sA[32768];   // [128 rows][256 B] swizzled
  __shared__ __align__(16) char sB[32768];
  int rb = blockIdx.x, cb = blockIdx.y;
  int t = threadIdx.x;
  const char* gA = (const char*)Zn   + (size_t)rb*32768;
  const char* gB = (const char*)Wcat + (size_t)cb*32768;
  #pragma unroll
  for (int it=0; it<8; ++it){
    int off = it*4096 + t*16;
    int row = off >> 8;
    int swz = off ^ ((row&7)<<4);
    *reinterpret_cast<i32x4*>(sA + swz) = *reinterpret_cast<const i32x4*>(gA + off);
    *reinterpret_cast<i32x4*>(sB + swz) = *reinterpret_cast<const i32x4*>(gB + off);
  }
  __syncthreads();
  int wid = t>>6, lane = t&63;
  int wr = wid>>1, wc = wid&1;
  int lcol = lane & 15, lk16 = (lane>>4)*16;
  f32x4 acc[4][4] = {};
  #pragma unroll
  for (int ks=0; ks<4; ++ks){
    bf16x8 a[4], b[4];
    #pragma unroll
    for (int mi=0; mi<4; ++mi){
      int row = wr*64 + mi*16 + lcol;
      int off = row*256 + ks*64 + lk16;
      a[mi] = *reinterpret_cast<const bf16x8*>(sA + (off ^ ((row&7)<<4)));
    }
    #pragma unroll
    for (int ni=0; ni<4; ++ni){
      int row = wc*64 + ni*16 + lcol;
      int off = row*256 + ks*64 + lk16;
      b[ni] = *reinterpret_cast<const bf16x8*>(sB + (off ^ ((row&7)<<4)));
    }
    #pragma unroll
    for (int mi=0; mi<4; ++mi)
      #pragma unroll
      for (int ni=0; ni<4; ++ni)
        acc[mi][ni] = __builtin_amdgcn_mfma_f32_16x16x32_bf16(a[mi], b[ni], acc[mi][ni], 0,0,0);
  }
  int r0 = (lane>>4)*4;
  if (cb <= 1){
    unsigned short* __restrict__ dst = cb ? Ksep : Qsep;
    #pragma unroll
    for (int mi=0; mi<4; ++mi)
      #pragma unroll
      for (int ni=0; ni<4; ++ni){
        int e = wc*64 + ni*16 + lcol;      // h = e>>5, c = e&31
        int hh = e>>5, c = e&31;
        int mrow = rb*128 + wr*64 + mi*16 + r0;
        #pragma unroll
        for (int r=0; r<4; ++r){
          int m = mrow + r;
          int i2 = m >> 8, j2 = m & 255;
          dst[(size_t)((i2*4 + hh)*256 + j2)*32 + c] = f2bf(acc[mi][ni][r]);
        }
      }
  } else if (cb == 3){
    #pragma unroll
    for (int mi=0; mi<4; ++mi)
      #pragma unroll
      for (int ni=0; ni<4; ++ni){
        int col = wc*64 + ni*16 + lcol;
        int mrow = rb*128 + wr*64 + mi*16 + r0;
        #pragma unroll
        for (int r=0; r<4; ++r)
          Gbuf[(size_t)(mrow+r)*128 + col] = f2bf(acc[mi][ni][r]);
      }
  } else { // cb == 2: v, transposed per (i,h)
    #pragma unroll
    for (int mi=0; mi<4; ++mi)
      #pragma unroll
      for (int ni=0; ni<4; ++ni){
        int e = wc*64 + ni*16 + lcol;
        int hh = e>>5, c = e&31;
        int mrow = rb*128 + wr*64 + mi*16 + r0;
        int i2 = mrow >> 8, j2 = mrow & 255;
        u16x4 pk;
        #pragma unroll
        for (int r=0; r<4; ++r) pk[r] = f2bf(acc[mi][ni][r]);
        *reinterpret_cast<u16x4*>(&Vt[(size_t)((i2*4 + hh)*32 + c)*256 + j2]) = pk;
      }
  }
}

// ---------------- kernel 4: attention, one block per (i, h) ------------------------
// Swapped QK^T (S^T lane-local softmax), online softmax over two 128-k halves.
// launch_bounds(256,2): on this toolchain 2nd arg acts as 2x waves/EU
// (round-3: arg 3 -> 84 VGPR = 512/6), so arg 2 -> cap 128 = 4 waves/SIMD bucket.
// sP XOR-swizzled: round-6's unswizzled [16q][64B] concentrated 64 lanes into
// 16 banks (8.4M conflict cycles). half-loop unroll 1 keeps one half's bias live.
__global__ __launch_bounds__(256, 2) void attn_kernel(
    const unsigned short* __restrict__ Qsep, const unsigned short* __restrict__ Ksep,
    const unsigned short* __restrict__ Vt, const float* __restrict__ bias4,
    const float* __restrict__ Z_mask, unsigned short* __restrict__ o_buf)
{
  __shared__ __align__(16) char sK[16384];   // [256 k-rows][64 B] swizzled
  __shared__ __align__(16) char sV[16384];   // [32 c-rows][512 B] swizzled
  __shared__ __align__(16) char sP[4096];    // per-wave 1 KiB: [16 q][64 B] XOR-swizzled
  __shared__ float smask[256];
  int ia = blockIdx.x >> 2, h = blockIdx.x & 3;
  int t = threadIdx.x;
  {
    const char* srcK = (const char*)&Ksep[(size_t)((ia*4 + h)*256)*32];
    const char* srcV = (const char*)&Vt[(size_t)((ia*4 + h)*32)*256];
    #pragma unroll
    for (int it=0; it<4; ++it){
      int off = (it*256 + t)*16;
      int rowK = off >> 6;
      *reinterpret_cast<i32x4*>(sK + (off ^ ((rowK&7)<<4))) =
        *reinterpret_cast<const i32x4*>(srcK + off);
      int rowV = off >> 9;
      *reinterpret_cast<i32x4*>(sV + (off ^ ((rowV&7)<<4))) =
        *reinterpret_cast<const i32x4*>(srcV + off);
    }
  }
  smask[t] = 1e9f * (Z_mask[(size_t)t*256 + ia] - 1.0f);
  __syncthreads();

  int wid = t>>6, lane = t&63;
  int lq = lane & 15;
  int hi = lane >> 4;
  char* sPw = sP + wid*1024;
  int pswz = (lq&7)<<4;   // sP XOR swizzle (bijective within the 1 KiB chunk)
  const f32x4* b4 = reinterpret_cast<const f32x4*>(bias4);

  #pragma unroll 1
  for (int mi=0; mi<4; ++mi){
    int q0 = wid*64 + mi*16;
    int q  = q0 + lq;
    bf16x8 aq = *reinterpret_cast<const bf16x8*>(
        &Qsep[(size_t)((ia*4 + h)*256 + q)*32 + hi*8]);
    f32x4 oacc[2] = {};
    float mrun = 0.f, lsum = 0.f;
    #pragma unroll 1
    for (int half=0; half<2; ++half){
      f32x4 s[8];
      // C-init = bias4[h][g][q] + mask[k0..k0+3]
      #pragma unroll
      for (int ni=0; ni<8; ++ni){
        int g  = half*32 + ni*4 + hi;
        int k0 = half*128 + ni*16 + hi*4;
        f32x4 bb  = b4[(size_t)(h*64 + g)*256 + q];
        f32x4 msk = *reinterpret_cast<const f32x4*>(&smask[k0]);
        s[ni] = bb + msk;
      }
      // swapped QK^T: A=K-frag, B=Q-frag -> S^T (row=k, col=q)
      #pragma unroll
      for (int ni=0; ni<8; ++ni){
        int krow = half*128 + ni*16 + lq;
        int off  = krow*64 + hi*16;
        bf16x8 bk = *reinterpret_cast<const bf16x8*>(sK + (off ^ ((krow&7)<<4)));
        s[ni] = __builtin_amdgcn_mfma_f32_16x16x32_bf16(bk, aq, s[ni], 0,0,0);
      }
      // row max for q-row (q0+lq): lane-local + peers at ^16, ^32
      f32x4 m4 = fmax4(s[0], s[1]);
      m4 = fmax4(m4, fmax4(s[2], s[3]));
      m4 = fmax4(m4, fmax4(s[4], s[5]));
      m4 = fmax4(m4, fmax4(s[6], s[7]));
      float mx = fmaxf(fmaxf(m4[0], m4[1]), fmaxf(m4[2], m4[3]));
      mx = fmaxf(mx, __shfl_xor(mx, 16, 64));
      mx = fmaxf(mx, __shfl_xor(mx, 32, 64));
      if (half == 0){
        mrun = mx;
      } else {
        float mnew = fmaxf(mrun, mx);
        float sc = __expf(mrun - mnew);   // scale for q-row (q0+lq)
        lsum *= sc;
        mrun = mnew;
        // oacc rows are q = q0 + hi*4 + r -> fetch those rows' scales
        #pragma unroll
        for (int r=0; r<4; ++r){
          float scr = __shfl(sc, hi*4 + r, 64);
          oacc[0][r] *= scr;
          oacc[1][r] *= scr;
        }
      }
      // exp + partial sum
      f32x4 sum4 = {0.f,0.f,0.f,0.f};
      #pragma unroll
      for (int ni=0; ni<8; ++ni){
        f32x4 p;
        #pragma unroll
        for (int r=0; r<4; ++r) p[r] = __expf(s[ni][r] - mrun);
        s[ni] = p;
        sum4 += p;
      }
      lsum += (sum4[0]+sum4[1]) + (sum4[2]+sum4[3]);
      // pack P -> bf16 through wave-private sP (XOR-swizzled), PV in 32-k chunks
      #pragma unroll
      for (int ck=0; ck<4; ++ck){
        #pragma unroll
        for (int nl=0; nl<2; ++nl){
          int ni = ck*2 + nl;
          u32x2 w;
          w.x = packbf2(s[ni][0], s[ni][1]);
          w.y = packbf2(s[ni][2], s[ni][3]);
          *reinterpret_cast<u32x2*>(sPw + ((lq*64 + nl*32 + hi*8) ^ pswz)) = w;
        }
        bf16x8 ap = *reinterpret_cast<const bf16x8*>(sPw + ((lq*64 + hi*16) ^ pswz));
        int ks = half*4 + ck;
        #pragma unroll
        for (int nc=0; nc<2; ++nc){
          int vrow = nc*16 + lq;
          int voff = vrow*512 + ks*64 + hi*16;
          bf16x8 bv = *reinterpret_cast<const bf16x8*>(sV + (voff ^ ((vrow&7)<<4)));
          oacc[nc] = __builtin_amdgcn_mfma_f32_16x16x32_bf16(ap, bv, oacc[nc], 0,0,0);
        }
      }
    }
    float sum = lsum;
    sum += __shfl_xor(sum, 16, 64);
    sum += __shfl_xor(sum, 32, 64);
    float rinv[4];
    #pragma unroll
    for (int r=0; r<4; ++r)
      rinv[r] = __builtin_amdgcn_rcpf(__shfl(sum, hi*4 + r, 64));
    #pragma unroll
    for (int nc=0; nc<2; ++nc)
      #pragma unroll
      for (int r=0; r<4; ++r){
        int qo = q0 + hi*4 + r;
        o_buf[(size_t)(ia*256 + qo)*128 + h*32 + nc*16 + lq] = f2bf(oacc[nc][r] * rinv[r]);
      }
  }
}

// ---------------- kernel 5: gate * o @ w_o^T + out_bias + Z_raw (transposed out) ----
__global__ __launch_bounds__(256) void final_kernel(
    const unsigned short* __restrict__ Gbuf, const unsigned short* __restrict__ o_buf,
    const unsigned short* __restrict__ Wo_bf, const float* __restrict__ b_g,
    const float* __restrict__ out_bias, const float* __restrict__ Z_raw,
    float* __restrict__ out)
{
  __shared__ __align__(16) char sA[32768];
  __shared__ __align__(16) char sB[32768];
  int rb = blockIdx.x, t = threadIdx.x;
  #pragma unroll
  for (int it=0; it<8; ++it){
    int idx = (it*256 + t)*8;
    int row = idx >> 7, e0 = idx & 127;
    size_t m = (size_t)rb*128 + row;
    bf16x8 gv = *reinterpret_cast<const bf16x8*>(&Gbuf[m*128 + e0]);
    bf16x8 ov = *reinterpret_cast<const bf16x8*>(&o_buf[m*128 + e0]);
    bf16x8 av;
    #pragma unroll
    for (int jj=0; jj<8; ++jj){
      float g  = bf2f((unsigned short)gv[jj]) + b_g[e0+jj];
      float sg = 1.0f/(1.0f + __expf(-g));
      av[jj] = (short)f2bf(sg * bf2f((unsigned short)ov[jj]));
    }
    int off = idx*2;
    *reinterpret_cast<bf16x8*>(sA + (off ^ ((row&7)<<4))) = av;
    *reinterpret_cast<i32x4*>(sB + (off ^ ((row&7)<<4))) =
      *reinterpret_cast<const i32x4*>(&Wo_bf[idx]);
  }
  __syncthreads();
  int wid = t>>6, lane = t&63;
  int wr = wid>>1, wc = wid&1;
  int lcol = lane & 15, lk16 = (lane>>4)*16;
  f32x4 acc[4][4] = {};
  #pragma unroll
  for (int ks=0; ks<4; ++ks){
    bf16x8 a[4], b[4];
    #pragma unroll
    for (int mi=0; mi<4; ++mi){
      int row = wr*64 + mi*16 + lcol;
      int off = row*256 + ks*64 + lk16;
      a[mi] = *reinterpret_cast<const bf16x8*>(sA + (off ^ ((row&7)<<4)));
    }
    #pragma unroll
    for (int ni=0; ni<4; ++ni){
      int row = wc*64 + ni*16 + lcol;
      int off = row*256 + ks*64 + lk16;
      b[ni] = *reinterpret_cast<const bf16x8*>(sB + (off ^ ((row&7)<<4)));
    }
    #pragma unroll
    for (int mi=0; mi<4; ++mi)
      #pragma unroll
      for (int ni=0; ni<4; ++ni)
        acc[mi][ni] = __builtin_amdgcn_mfma_f32_16x16x32_bf16(a[mi], b[ni], acc[mi][ni], 0,0,0);
  }
  int r0 = (lane>>4)*4;
  #pragma unroll
  for (int mi=0; mi<4; ++mi)
    #pragma unroll
    for (int ni=0; ni<4; ++ni){
      int col = wc*64 + ni*16 + lcol;
      #pragma unroll
      for (int r=0; r<4; ++r){
        int mrow = rb*128 + wr*64 + mi*16 + r0 + r;
        int i = mrow >> 8, j = mrow & 255;
        size_t oidx = ((size_t)(j*256 + i))*128 + col;
        out[oidx] = acc[mi][ni][r] + out_bias[col] + Z_raw[oidx];
      }
    }
}

extern "C" void kernel_launch(void* const* d_in, const int* in_sizes, int n_in,
                              void* d_out, int out_size, void* d_ws, size_t ws_size,
                              hipStream_t stream)
{
  (void)in_sizes; (void)n_in; (void)out_size; (void)ws_size;
  const float* Z_raw    = (const float*)d_in[0];
  const float* Z_mask   = (const float*)d_in[1];
  const float* ln_gamma = (const float*)d_in[2];
  const float* ln_beta  = (const float*)d_in[3];
  const float* w_b      = (const float*)d_in[4];
  const float* w_qkv    = (const float*)d_in[5];
  const float* w_g      = (const float*)d_in[6];
  const float* b_g      = (const float*)d_in[7];
  const float* w_o      = (const float*)d_in[8];
  const float* out_bias = (const float*)d_in[9];
  float* out = (float*)d_out;

  char* ws = (char*)d_ws;
  unsigned short* Zn    = (unsigned short*)(ws + ZN_OFF);
  unsigned short* Qsep  = (unsigned short*)(ws + QSEP_OFF);
  unsigned short* Ksep  = (unsigned short*)(ws + KSEP_OFF);
  unsigned short* Gbuf  = (unsigned short*)(ws + GBUF_OFF);
  unsigned short* Vt    = (unsigned short*)(ws + VT_OFF);
  float*          biasb = (float*)(ws + BIAS_OFF);
  unsigned short* Wcat  = (unsigned short*)(ws + WCAT_OFF);
  unsigned short* Wo_bf = (unsigned short*)(ws + WO_OFF);
  unsigned short* o_buf = Zn;   // alias: Zn dead after GEMM

  prep_kernel<<<dim3(320), dim3(256), 0, stream>>>(w_qkv, w_g, w_o, Wcat, Wo_bf);
  ln_bias_kernel<<<dim3(16384), dim3(256), 0, stream>>>(Z_raw, ln_gamma, ln_beta, w_b, Zn, biasb);
  gemm_qkvg_kernel<<<dim3(512, 4), dim3(256), 0, stream>>>(Zn, Wcat, Qsep, Ksep, Gbuf, Vt);
  attn_kernel<<<dim3(1024), dim3(256), 0, stream>>>(Qsep, Ksep, Vt, biasb, Z_mask, o_buf);
  final_kernel<<<dim3(512), dim3(256), 0, stream>>>(Gbuf, o_buf, Wo_bf, b_g, out_bias, Z_raw, out);
}

// Round 8
// 99.928 us; speedup vs baseline: 2.9265x; 1.1389x over previous
//
#include <hip/hip_runtime.h>

typedef __attribute__((ext_vector_type(4))) float  f32x4;
typedef __attribute__((ext_vector_type(8))) short  bf16x8;
typedef __attribute__((ext_vector_type(4))) int    i32x4;
typedef __attribute__((ext_vector_type(2))) unsigned short u16x2;
typedef __attribute__((ext_vector_type(4))) unsigned short u16x4;
typedef __attribute__((ext_vector_type(2))) unsigned int   u32x2;

// ws layout (bytes)
#define ZN_OFF    0u            // 65536*128 bf16 = 16 MiB (aliased as o_buf after GEMM+bias)
#define QSEP_OFF  16777216u     // [256 i][4 h][256 j][32 c] bf16 = 16 MiB (q, scale folded)
#define KSEP_OFF  33554432u     // [256 i][4 h][256 j][32 c] bf16 = 16 MiB
#define GBUF_OFF  50331648u     // [65536][128] bf16 = 16 MiB (gate)
#define VT_OFF    67108864u     // [256 i][4 h][32 c][256 j] bf16 = 16 MiB
#define BIAS_OFF  83886080u     // [4 h][64 k4][256 q][4] f32 = 1 MiB (gathered-transpose)
#define WCAT_OFF  84934656u     // [516][128] bf16 (q-scaled, k, v, g, w_b rows 512-515)
#define WO_OFF    85066752u     // [128][128] bf16

__device__ __forceinline__ unsigned short f2bf(float x){
  unsigned int u = __builtin_bit_cast(unsigned int, x);
  unsigned int r = (u + 0x7FFFu + ((u>>16)&1u)) >> 16;
  return (unsigned short)r;
}
__device__ __forceinline__ float bf2f(unsigned short b){
  unsigned int u = ((unsigned int)b) << 16;
  return __builtin_bit_cast(float, u);
}
__device__ __forceinline__ f32x4 fmax4(f32x4 a, f32x4 b){
  f32x4 r; r[0]=fmaxf(a[0],b[0]); r[1]=fmaxf(a[1],b[1]);
  r[2]=fmaxf(a[2],b[2]); r[3]=fmaxf(a[3],b[3]); return r;
}
__device__ __forceinline__ unsigned packbf2(float lo, float hi){
  return __builtin_amdgcn_perm(__builtin_bit_cast(unsigned, hi),
                               __builtin_bit_cast(unsigned, lo), 0x07060302u);
}

// ---------------- kernel 1: weight prep (fp32 -> bf16, fold q scale) ----------------
// Wcat rows: 0-127 q (scaled), 128-255 k, 256-383 v, 384-511 g, 512-515 w_b.
__global__ __launch_bounds__(256) void prep_kernel(
    const float* __restrict__ w_qkv, const float* __restrict__ w_g,
    const float* __restrict__ w_b,  const float* __restrict__ w_o,
    unsigned short* __restrict__ Wcat, unsigned short* __restrict__ Wo_bf)
{
  int idx = blockIdx.x*256 + threadIdx.x;
  if (idx < 516*128){
    int r = idx >> 7, d = idx & 127;
    float v;
    if (r < 384)      v = w_qkv[idx];
    else if (r < 512) v = w_g[(r-384)*128 + d];
    else              v = w_b[(r-512)*128 + d];
    if (r < 128) v *= 0.17677669529663689f;   // C^-0.5 folded into q rows
    Wcat[idx] = f2bf(v);
  } else if (idx < 516*128 + 128*128){
    int k = idx - 516*128;
    Wo_bf[k] = f2bf(w_o[k]);
  }
}

// ---------------- kernel 2: LayerNorm only (of transposed Z_raw) -------------------
// 32 lanes per row (float4/lane), 2 rows/wave: butterfly masks 1..16 only (no
// xor-32 ds_permute-class step). Round-7 diagnosis: the old 64-lane version's
// 36 shuffle steps/row (12 crossing DPP rows) were the latency chain.
__global__ __launch_bounds__(256) void ln_kernel(
    const float* __restrict__ Z_raw, const float* __restrict__ ln_gamma,
    const float* __restrict__ ln_beta, unsigned short* __restrict__ Zn)
{
  int wid = threadIdx.x >> 6, lane = threadIdx.x & 63;
  int half = lane >> 5, l32 = lane & 31;
  int m = blockIdx.x*8 + wid*2 + half;
  int i = m >> 8, j = m & 255;
  f32x4 v = *reinterpret_cast<const f32x4*>(&Z_raw[((size_t)(j*256 + i))*128 + l32*4]);
  float s  = (v[0]+v[1]) + (v[2]+v[3]);
  float sq = (v[0]*v[0]+v[1]*v[1]) + (v[2]*v[2]+v[3]*v[3]);
  #pragma unroll
  for (int mk=1; mk<32; mk<<=1){ s += __shfl_xor(s, mk, 64); sq += __shfl_xor(sq, mk, 64); }
  float mu   = s * (1.0f/128.0f);
  float var  = sq*(1.0f/128.0f) - mu*mu;
  float rstd = rsqrtf(var + 1e-5f);
  f32x4 g4 = *reinterpret_cast<const f32x4*>(&ln_gamma[l32*4]);
  f32x4 b4 = *reinterpret_cast<const f32x4*>(&ln_beta[l32*4]);
  u16x4 o;
  #pragma unroll
  for (int t=0; t<4; ++t) o[t] = f2bf((v[t]-mu)*rstd*g4[t] + b4[t]);
  *reinterpret_cast<u16x4*>(&Zn[(size_t)m*128 + l32*4]) = o;
}

// ---------------- kernel 2b: pair-bias via MFMA [65536x128] x [128x4] --------------
// A-frag: Zn rows (lane holds row m0+lcol); B-frag: w_b row lcol (col=head).
// C[row][col]: row = m0+hi*4+r, col = lcol(=h). Store = one contiguous f32x4.
__global__ __launch_bounds__(256) void bias_kernel(
    const unsigned short* __restrict__ Zn, const unsigned short* __restrict__ Wcat,
    float* __restrict__ bias4)
{
  int wid = threadIdx.x >> 6, lane = threadIdx.x & 63;
  int lcol = lane & 15, hi = lane >> 4;
  int gw = blockIdx.x*4 + wid;
  bf16x8 wb[4];
  #pragma unroll
  for (int ks=0; ks<4; ++ks){
    if (lcol < 4)
      wb[ks] = *reinterpret_cast<const bf16x8*>(&Wcat[(512+lcol)*128 + ks*32 + hi*8]);
    else
      wb[ks] = (bf16x8){0,0,0,0,0,0,0,0};
  }
  #pragma unroll
  for (int st=0; st<4; ++st){
    int m0 = gw*64 + st*16;
    f32x4 acc = {0.f,0.f,0.f,0.f};
    #pragma unroll
    for (int ks=0; ks<4; ++ks){
      bf16x8 a = *reinterpret_cast<const bf16x8*>(&Zn[(size_t)(m0+lcol)*128 + ks*32 + hi*8]);
      acc = __builtin_amdgcn_mfma_f32_16x16x32_bf16(a, wb[ks], acc, 0,0,0);
    }
    if (lcol < 4){
      int mr = m0 + hi*4;
      int i2 = mr >> 8, jb = mr & 255;
      *reinterpret_cast<f32x4*>(&bias4[((size_t)(lcol*64 + (jb>>2))*256 + i2)*4]) = acc;
    }
  }
}

// ---------------- kernel 3: fused qkv+g GEMM [65536x128] x [128x512] ---------------
// cb 0: q -> Qsep[i][h][j][c] ; cb 1: k -> Ksep ; cb 2: v -> Vt ; cb 3: g -> Gbuf
__global__ __launch_bounds__(256) void gemm_qkvg_kernel(
    const unsigned short* __restrict__ Zn, const unsigned short* __restrict__ Wcat,
    unsigned short* __restrict__ Qsep, unsigned short* __restrict__ Ksep,
    unsigned short* __restrict__ Gbuf, unsigned short* __restrict__ Vt)
{
  __shared__ __align__(16) char sA[32768];   // [128 rows][256 B] swizzled
  __shared__ __align__(16) char sB[32768];
  int rb = blockIdx.x, cb = blockIdx.y;
  int t = threadIdx.x;
  const char* gA = (const char*)Zn   + (size_t)rb*32768;
  const char* gB = (const char*)Wcat + (size_t)cb*32768;
  #pragma unroll
  for (int it=0; it<8; ++it){
    int off = it*4096 + t*16;
    int row = off >> 8;
    int swz = off ^ ((row&7)<<4);
    *reinterpret_cast<i32x4*>(sA + swz) = *reinterpret_cast<const i32x4*>(gA + off);
    *reinterpret_cast<i32x4*>(sB + swz) = *reinterpret_cast<const i32x4*>(gB + off);
  }
  __syncthreads();
  int wid = t>>6, lane = t&63;
  int wr = wid>>1, wc = wid&1;
  int lcol = lane & 15, lk16 = (lane>>4)*16;
  f32x4 acc[4][4] = {};
  #pragma unroll
  for (int ks=0; ks<4; ++ks){
    bf16x8 a[4], b[4];
    #pragma unroll
    for (int mi=0; mi<4; ++mi){
      int row = wr*64 + mi*16 + lcol;
      int off = row*256 + ks*64 + lk16;
      a[mi] = *reinterpret_cast<const bf16x8*>(sA + (off ^ ((row&7)<<4)));
    }
    #pragma unroll
    for (int ni=0; ni<4; ++ni){
      int row = wc*64 + ni*16 + lcol;
      int off = row*256 + ks*64 + lk16;
      b[ni] = *reinterpret_cast<const bf16x8*>(sB + (off ^ ((row&7)<<4)));
    }
    #pragma unroll
    for (int mi=0; mi<4; ++mi)
      #pragma unroll
      for (int ni=0; ni<4; ++ni)
        acc[mi][ni] = __builtin_amdgcn_mfma_f32_16x16x32_bf16(a[mi], b[ni], acc[mi][ni], 0,0,0);
  }
  int r0 = (lane>>4)*4;
  if (cb <= 1){
    unsigned short* __restrict__ dst = cb ? Ksep : Qsep;
    #pragma unroll
    for (int mi=0; mi<4; ++mi)
      #pragma unroll
      for (int ni=0; ni<4; ++ni){
        int e = wc*64 + ni*16 + lcol;      // h = e>>5, c = e&31
        int hh = e>>5, c = e&31;
        int mrow = rb*128 + wr*64 + mi*16 + r0;
        #pragma unroll
        for (int r=0; r<4; ++r){
          int m = mrow + r;
          int i2 = m >> 8, j2 = m & 255;
          dst[(size_t)((i2*4 + hh)*256 + j2)*32 + c] = f2bf(acc[mi][ni][r]);
        }
      }
  } else if (cb == 3){
    #pragma unroll
    for (int mi=0; mi<4; ++mi)
      #pragma unroll
      for (int ni=0; ni<4; ++ni){
        int col = wc*64 + ni*16 + lcol;
        int mrow = rb*128 + wr*64 + mi*16 + r0;
        #pragma unroll
        for (int r=0; r<4; ++r)
          Gbuf[(size_t)(mrow+r)*128 + col] = f2bf(acc[mi][ni][r]);
      }
  } else { // cb == 2: v, transposed per (i,h)
    #pragma unroll
    for (int mi=0; mi<4; ++mi)
      #pragma unroll
      for (int ni=0; ni<4; ++ni){
        int e = wc*64 + ni*16 + lcol;
        int hh = e>>5, c = e&31;
        int mrow = rb*128 + wr*64 + mi*16 + r0;
        int i2 = mrow >> 8, j2 = mrow & 255;
        u16x4 pk;
        #pragma unroll
        for (int r=0; r<4; ++r) pk[r] = f2bf(acc[mi][ni][r]);
        *reinterpret_cast<u16x4*>(&Vt[(size_t)((i2*4 + hh)*32 + c)*256 + j2]) = pk;
      }
  }
}

// ---------------- kernel 4: attention, one block per (i, h) ------------------------
// Swapped QK^T (S^T lane-local softmax), online softmax over two 128-k halves.
// launch_bounds(256,2): on this toolchain 2nd arg acts as 2x waves/EU
// (round-3: arg 3 -> 84 VGPR = 512/6), so arg 2 -> cap 128 = 4 waves/SIMD bucket.
// sP XOR-swizzled (round-6: unswizzled cost 8.4M conflict cycles).
__global__ __launch_bounds__(256, 2) void attn_kernel(
    const unsigned short* __restrict__ Qsep, const unsigned short* __restrict__ Ksep,
    const unsigned short* __restrict__ Vt, const float* __restrict__ bias4,
    const float* __restrict__ Z_mask, unsigned short* __restrict__ o_buf)
{
  __shared__ __align__(16) char sK[16384];   // [256 k-rows][64 B] swizzled
  __shared__ __align__(16) char sV[16384];   // [32 c-rows][512 B] swizzled
  __shared__ __align__(16) char sP[4096];    // per-wave 1 KiB: [16 q][64 B] XOR-swizzled
  __shared__ float smask[256];
  int ia = blockIdx.x >> 2, h = blockIdx.x & 3;
  int t = threadIdx.x;
  {
    const char* srcK = (const char*)&Ksep[(size_t)((ia*4 + h)*256)*32];
    const char* srcV = (const char*)&Vt[(size_t)((ia*4 + h)*32)*256];
    #pragma unroll
    for (int it=0; it<4; ++it){
      int off = (it*256 + t)*16;
      int rowK = off >> 6;
      *reinterpret_cast<i32x4*>(sK + (off ^ ((rowK&7)<<4))) =
        *reinterpret_cast<const i32x4*>(srcK + off);
      int rowV = off >> 9;
      *reinterpret_cast<i32x4*>(sV + (off ^ ((rowV&7)<<4))) =
        *reinterpret_cast<const i32x4*>(srcV + off);
    }
  }
  smask[t] = 1e9f * (Z_mask[(size_t)t*256 + ia] - 1.0f);
  __syncthreads();

  int wid = t>>6, lane = t&63;
  int lq = lane & 15;
  int hi = lane >> 4;
  char* sPw = sP + wid*1024;
  int pswz = (lq&7)<<4;   // sP XOR swizzle (bijective within the 1 KiB chunk)
  const f32x4* b4 = reinterpret_cast<const f32x4*>(bias4);

  #pragma unroll 1
  for (int mi=0; mi<4; ++mi){
    int q0 = wid*64 + mi*16;
    int q  = q0 + lq;
    bf16x8 aq = *reinterpret_cast<const bf16x8*>(
        &Qsep[(size_t)((ia*4 + h)*256 + q)*32 + hi*8]);
    f32x4 oacc[2] = {};
    float mrun = 0.f, lsum = 0.f;
    #pragma unroll 1
    for (int half=0; half<2; ++half){
      f32x4 s[8];
      // C-init = bias4[h][g][q] + mask[k0..k0+3]
      #pragma unroll
      for (int ni=0; ni<8; ++ni){
        int g  = half*32 + ni*4 + hi;
        int k0 = half*128 + ni*16 + hi*4;
        f32x4 bb  = b4[(size_t)(h*64 + g)*256 + q];
        f32x4 msk = *reinterpret_cast<const f32x4*>(&smask[k0]);
        s[ni] = bb + msk;
      }
      // swapped QK^T: A=K-frag, B=Q-frag -> S^T (row=k, col=q)
      #pragma unroll
      for (int ni=0; ni<8; ++ni){
        int krow = half*128 + ni*16 + lq;
        int off  = krow*64 + hi*16;
        bf16x8 bk = *reinterpret_cast<const bf16x8*>(sK + (off ^ ((krow&7)<<4)));
        s[ni] = __builtin_amdgcn_mfma_f32_16x16x32_bf16(bk, aq, s[ni], 0,0,0);
      }
      // row max for q-row (q0+lq): lane-local + peers at ^16, ^32
      f32x4 m4 = fmax4(s[0], s[1]);
      m4 = fmax4(m4, fmax4(s[2], s[3]));
      m4 = fmax4(m4, fmax4(s[4], s[5]));
      m4 = fmax4(m4, fmax4(s[6], s[7]));
      float mx = fmaxf(fmaxf(m4[0], m4[1]), fmaxf(m4[2], m4[3]));
      mx = fmaxf(mx, __shfl_xor(mx, 16, 64));
      mx = fmaxf(mx, __shfl_xor(mx, 32, 64));
      if (half == 0){
        mrun = mx;
      } else {
        float mnew = fmaxf(mrun, mx);
        float sc = __expf(mrun - mnew);   // scale for q-row (q0+lq)
        lsum *= sc;
        mrun = mnew;
        // oacc rows are q = q0 + hi*4 + r -> fetch those rows' scales
        #pragma unroll
        for (int r=0; r<4; ++r){
          float scr = __shfl(sc, hi*4 + r, 64);
          oacc[0][r] *= scr;
          oacc[1][r] *= scr;
        }
      }
      // exp + partial sum
      f32x4 sum4 = {0.f,0.f,0.f,0.f};
      #pragma unroll
      for (int ni=0; ni<8; ++ni){
        f32x4 p;
        #pragma unroll
        for (int r=0; r<4; ++r) p[r] = __expf(s[ni][r] - mrun);
        s[ni] = p;
        sum4 += p;
      }
      lsum += (sum4[0]+sum4[1]) + (sum4[2]+sum4[3]);
      // pack P -> bf16 through wave-private sP (XOR-swizzled), PV in 32-k chunks
      #pragma unroll
      for (int ck=0; ck<4; ++ck){
        #pragma unroll
        for (int nl=0; nl<2; ++nl){
          int ni = ck*2 + nl;
          u32x2 w;
          w.x = packbf2(s[ni][0], s[ni][1]);
          w.y = packbf2(s[ni][2], s[ni][3]);
          *reinterpret_cast<u32x2*>(sPw + ((lq*64 + nl*32 + hi*8) ^ pswz)) = w;
        }
        bf16x8 ap = *reinterpret_cast<const bf16x8*>(sPw + ((lq*64 + hi*16) ^ pswz));
        int ks = half*4 + ck;
        #pragma unroll
        for (int nc=0; nc<2; ++nc){
          int vrow = nc*16 + lq;
          int voff = vrow*512 + ks*64 + hi*16;
          bf16x8 bv = *reinterpret_cast<const bf16x8*>(sV + (voff ^ ((vrow&7)<<4)));
          oacc[nc] = __builtin_amdgcn_mfma_f32_16x16x32_bf16(ap, bv, oacc[nc], 0,0,0);
        }
      }
    }
    float sum = lsum;
    sum += __shfl_xor(sum, 16, 64);
    sum += __shfl_xor(sum, 32, 64);
    float rinv[4];
    #pragma unroll
    for (int r=0; r<4; ++r)
      rinv[r] = __builtin_amdgcn_rcpf(__shfl(sum, hi*4 + r, 64));
    #pragma unroll
    for (int nc=0; nc<2; ++nc)
      #pragma unroll
      for (int r=0; r<4; ++r){
        int qo = q0 + hi*4 + r;
        o_buf[(size_t)(ia*256 + qo)*128 + h*32 + nc*16 + lq] = f2bf(oacc[nc][r] * rinv[r]);
      }
  }
}

// ---------------- kernel 5: gate * o @ w_o^T + out_bias + Z_raw (transposed out) ----
__global__ __launch_bounds__(256) void final_kernel(
    const unsigned short* __restrict__ Gbuf, const unsigned short* __restrict__ o_buf,
    const unsigned short* __restrict__ Wo_bf, const float* __restrict__ b_g,
    const float* __restrict__ out_bias, const float* __restrict__ Z_raw,
    float* __restrict__ out)
{
  __shared__ __align__(16) char sA[32768];
  __shared__ __align__(16) char sB[32768];
  int rb = blockIdx.x, t = threadIdx.x;
  #pragma unroll
  for (int it=0; it<8; ++it){
    int idx = (it*256 + t)*8;
    int row = idx >> 7, e0 = idx & 127;
    size_t m = (size_t)rb*128 + row;
    bf16x8 gv = *reinterpret_cast<const bf16x8*>(&Gbuf[m*128 + e0]);
    bf16x8 ov = *reinterpret_cast<const bf16x8*>(&o_buf[m*128 + e0]);
    bf16x8 av;
    #pragma unroll
    for (int jj=0; jj<8; ++jj){
      float g  = bf2f((unsigned short)gv[jj]) + b_g[e0+jj];
      float sg = 1.0f/(1.0f + __expf(-g));
      av[jj] = (short)f2bf(sg * bf2f((unsigned short)ov[jj]));
    }
    int off = idx*2;
    *reinterpret_cast<bf16x8*>(sA + (off ^ ((row&7)<<4))) = av;
    *reinterpret_cast<i32x4*>(sB + (off ^ ((row&7)<<4))) =
      *reinterpret_cast<const i32x4*>(&Wo_bf[idx]);
  }
  __syncthreads();
  int wid = t>>6, lane = t&63;
  int wr = wid>>1, wc = wid&1;
  int lcol = lane & 15, lk16 = (lane>>4)*16;
  f32x4 acc[4][4] = {};
  #pragma unroll
  for (int ks=0; ks<4; ++ks){
    bf16x8 a[4], b[4];
    #pragma unroll
    for (int mi=0; mi<4; ++mi){
      int row = wr*64 + mi*16 + lcol;
      int off = row*256 + ks*64 + lk16;
      a[mi] = *reinterpret_cast<const bf16x8*>(sA + (off ^ ((row&7)<<4)));
    }
    #pragma unroll
    for (int ni=0; ni<4; ++ni){
      int row = wc*64 + ni*16 + lcol;
      int off = row*256 + ks*64 + lk16;
      b[ni] = *reinterpret_cast<const bf16x8*>(sB + (off ^ ((row&7)<<4)));
    }
    #pragma unroll
    for (int mi=0; mi<4; ++mi)
      #pragma unroll
      for (int ni=0; ni<4; ++ni)
        acc[mi][ni] = __builtin_amdgcn_mfma_f32_16x16x32_bf16(a[mi], b[ni], acc[mi][ni], 0,0,0);
  }
  int r0 = (lane>>4)*4;
  #pragma unroll
  for (int mi=0; mi<4; ++mi)
    #pragma unroll
    for (int ni=0; ni<4; ++ni){
      int col = wc*64 + ni*16 + lcol;
      #pragma unroll
      for (int r=0; r<4; ++r){
        int mrow = rb*128 + wr*64 + mi*16 + r0 + r;
        int i = mrow >> 8, j = mrow & 255;
        size_t oidx = ((size_t)(j*256 + i))*128 + col;
        out[oidx] = acc[mi][ni][r] + out_bias[col] + Z_raw[oidx];
      }
    }
}

extern "C" void kernel_launch(void* const* d_in, const int* in_sizes, int n_in,
                              void* d_out, int out_size, void* d_ws, size_t ws_size,
                              hipStream_t stream)
{
  (void)in_sizes; (void)n_in; (void)out_size; (void)ws_size;
  const float* Z_raw    = (const float*)d_in[0];
  const float* Z_mask   = (const float*)d_in[1];
  const float* ln_gamma = (const float*)d_in[2];
  const float* ln_beta  = (const float*)d_in[3];
  const float* w_b      = (const float*)d_in[4];
  const float* w_qkv    = (const float*)d_in[5];
  const float* w_g      = (const float*)d_in[6];
  const float* b_g      = (const float*)d_in[7];
  const float* w_o      = (const float*)d_in[8];
  const float* out_bias = (const float*)d_in[9];
  float* out = (float*)d_out;

  char* ws = (char*)d_ws;
  unsigned short* Zn    = (unsigned short*)(ws + ZN_OFF);
  unsigned short* Qsep  = (unsigned short*)(ws + QSEP_OFF);
  unsigned short* Ksep  = (unsigned short*)(ws + KSEP_OFF);
  unsigned short* Gbuf  = (unsigned short*)(ws + GBUF_OFF);
  unsigned short* Vt    = (unsigned short*)(ws + VT_OFF);
  float*          biasb = (float*)(ws + BIAS_OFF);
  unsigned short* Wcat  = (unsigned short*)(ws + WCAT_OFF);
  unsigned short* Wo_bf = (unsigned short*)(ws + WO_OFF);
  unsigned short* o_buf = Zn;   // alias: Zn dead after gemm+bias kernels

  prep_kernel<<<dim3(322), dim3(256), 0, stream>>>(w_qkv, w_g, w_b, w_o, Wcat, Wo_bf);
  ln_kernel<<<dim3(8192), dim3(256), 0, stream>>>(Z_raw, ln_gamma, ln_beta, Zn);
  gemm_qkvg_kernel<<<dim3(512, 4), dim3(256), 0, stream>>>(Zn, Wcat, Qsep, Ksep, Gbuf, Vt);
  bias_kernel<<<dim3(256), dim3(256), 0, stream>>>(Zn, Wcat, biasb);
  attn_kernel<<<dim3(1024), dim3(256), 0, stream>>>(Qsep, Ksep, Vt, biasb, Z_mask, o_buf);
  final_kernel<<<dim3(512), dim3(256), 0, stream>>>(Gbuf, o_buf, Wo_bf, b_g, out_bias, Z_raw, out);
}